// Round 6
// baseline (305.833 us; speedup 1.0000x reference)
//
#include <hip/hip_runtime.h>
#include <math.h>

typedef unsigned short ushort_t;
typedef __attribute__((ext_vector_type(8))) short short8;
typedef __attribute__((ext_vector_type(4))) float f32x4;

#define B_  16
#define HW_ 1024
#define C_  64
#define NC_ 5
#define D1_ 96
#define NH_ 4
#define DH_ 64

#define MFMA32(A,B,C) __builtin_amdgcn_mfma_f32_16x16x32_bf16(A,B,C,0,0,0)

__device__ __forceinline__ ushort_t f2bf(float f) {
    unsigned u = __float_as_uint(f);
    u = u + 0x7fffu + ((u >> 16) & 1u);   // round-to-nearest-even
    return (ushort_t)(u >> 16);
}

// truncating bf16 pair-pack: one v_perm-able op per 2 elements
__device__ __forceinline__ unsigned pack2_trunc(float lo, float hi) {
    return (__float_as_uint(hi) & 0xffff0000u) | (__float_as_uint(lo) >> 16);
}

// ---------------- K1: logits = xt @ wb_w + wb_b ; weight1 = softmax over classes ----------------
// 256 blocks x 64 threads: lane = hw (coalesced x), weights via scalar cache (uniform).
__global__ __launch_bounds__(64) void k1_logits(const float* __restrict__ x,
                                                const float* __restrict__ wb_w,
                                                const float* __restrict__ wb_b,
                                                float* __restrict__ logitsT,
                                                float* __restrict__ w1) {
    int b = blockIdx.x >> 4;
    int hw = (blockIdx.x & 15) * 64 + threadIdx.x;
    const float* xb = x + (size_t)b * C_ * HW_;
    float acc[NC_];
#pragma unroll
    for (int j = 0; j < NC_; j++) acc[j] = wb_b[j];
#pragma unroll 8
    for (int c = 0; c < C_; c++) {
        float xv = xb[c * HW_ + hw];
#pragma unroll
        for (int j = 0; j < NC_; j++) acc[j] += xv * wb_w[c * NC_ + j];
    }
    float m = acc[0];
#pragma unroll
    for (int j = 1; j < NC_; j++) m = fmaxf(m, acc[j]);
    float e[NC_], s = 0.f;
#pragma unroll
    for (int j = 0; j < NC_; j++) { e[j] = __expf(acc[j] - m); s += e[j]; }
    float inv = 1.f / s;
    int idx = b * HW_ + hw;
#pragma unroll
    for (int j = 0; j < NC_; j++) {
        logitsT[((size_t)b * NC_ + j) * HW_ + hw] = acc[j];
        w1[(size_t)idx * NC_ + j] = e[j] * inv;
    }
}

// ---------------- K2a: w2[b,c,:] = softmax over HW of logitsT[b,c,:] ----------------
__global__ __launch_bounds__(256) void k2a_softmax(const float* __restrict__ logitsT,
                                                   float* __restrict__ w2) {
    __shared__ float red[256];
    int t = threadIdx.x;
    const float* lp = logitsT + (size_t)blockIdx.x * HW_;
    float* wp = w2 + (size_t)blockIdx.x * HW_;
    float4 v = *(const float4*)(lp + t * 4);
    float lm = fmaxf(fmaxf(v.x, v.y), fmaxf(v.z, v.w));
#pragma unroll
    for (int off = 1; off < 64; off <<= 1) lm = fmaxf(lm, __shfl_xor(lm, off, 64));
    if ((t & 63) == 0) red[t >> 6] = lm;
    __syncthreads();
    float m = fmaxf(fmaxf(red[0], red[1]), fmaxf(red[2], red[3]));
    float e0 = __expf(v.x - m), e1 = __expf(v.y - m);
    float e2 = __expf(v.z - m), e3 = __expf(v.w - m);
    float ls = (e0 + e1) + (e2 + e3);
#pragma unroll
    for (int off = 1; off < 64; off <<= 1) ls += __shfl_xor(ls, off, 64);
    __syncthreads();
    if ((t & 63) == 0) red[t >> 6] = ls;
    __syncthreads();
    float inv = 1.f / (((red[0] + red[1]) + (red[2] + red[3])));
    float4 o = {e0 * inv, e1 * inv, e2 * inv, e3 * inv};
    *(float4*)(wp + t * 4) = o;
}

// ---------------- K2b: cf1[b,c,ch] = sum_hw w2[b,c,hw] * x[b,ch,hw] ----------------
__global__ __launch_bounds__(256) void k2b_pool(const float* __restrict__ x,
                                                const float* __restrict__ w2,
                                                float* __restrict__ cf1) {
    __shared__ float pl[NC_ * HW_];     // 20 KB
    int t = threadIdx.x;
    int b = blockIdx.x >> 4, chg = blockIdx.x & 15;
    const float* wb = w2 + (size_t)b * NC_ * HW_;
    for (int i = t; i < NC_ * HW_ / 4; i += 256)
        *(float4*)(pl + i * 4) = *(const float4*)(wb + i * 4);
    __syncthreads();
    int w = t >> 6, lane = t & 63;
    int ch = chg * 4 + w;
    const float* xc = x + ((size_t)b * C_ + ch) * HW_;
    float acc[NC_] = {0.f, 0.f, 0.f, 0.f, 0.f};
#pragma unroll
    for (int i = 0; i < HW_ / 64; i++) {
        int hw = i * 64 + lane;
        float xv = xc[hw];
#pragma unroll
        for (int c = 0; c < NC_; c++) acc[c] += xv * pl[c * HW_ + hw];
    }
#pragma unroll
    for (int c = 0; c < NC_; c++) {
        float a = acc[c];
#pragma unroll
        for (int off = 1; off < 64; off <<= 1) a += __shfl_xor(a, off, 64);
        if (lane == 0) cf1[((size_t)b * NC_ + c) * C_ + ch] = a;
    }
}

// ---------------- K3: MHA1 (n_head=1, dk=96, dv=64) + residual + LN, per batch ----------------
// kh/vh (memory projections) computed per-block in LDS (fused former k_kv).
__global__ __launch_bounds__(256) void k3_mha1(const float* __restrict__ cf1,
                                               const float* __restrict__ wq, const float* __restrict__ bq,
                                               const float* __restrict__ mem,
                                               const float* __restrict__ wk, const float* __restrict__ bk,
                                               const float* __restrict__ wv, const float* __restrict__ bv,
                                               const float* __restrict__ fc, const float* __restrict__ fcb,
                                               const float* __restrict__ lng, const float* __restrict__ lnb,
                                               float* __restrict__ cfs) {
    __shared__ float cs[NC_ * C_];
    __shared__ float kh[NC_ * D1_];
    __shared__ float vh[NC_ * DH_];
    __shared__ float q[NC_ * D1_];
    __shared__ float sc[NC_ * NC_];
    __shared__ float pp[NC_ * NC_];
    __shared__ float o[NC_ * C_];
    __shared__ float z[NC_ * C_];
    __shared__ float mu[NC_], rs[NC_];
    int t = threadIdx.x, b = blockIdx.x;
    for (int i = t; i < NC_ * C_; i += 256) cs[i] = cf1[(size_t)b * NC_ * C_ + i];
    for (int idx = t; idx < NC_ * D1_; idx += 256) {
        int i = idx / D1_, k = idx % D1_;
        float a = bk[k];
        for (int d = 0; d < D1_; d++) a += mem[i * D1_ + d] * wk[d * D1_ + k];
        kh[idx] = a;
    }
    for (int idx = t; idx < NC_ * DH_; idx += 256) {
        int i = idx / DH_, dv = idx % DH_;
        float a = bv[dv];
        for (int d = 0; d < D1_; d++) a += mem[i * D1_ + d] * wv[d * DH_ + dv];
        vh[idx] = a;
    }
    __syncthreads();
    for (int idx = t; idx < NC_ * D1_; idx += 256) {
        int i = idx / D1_, k = idx % D1_;
        float a = bq[k];
        for (int c = 0; c < C_; c++) a += cs[i * C_ + c] * wq[c * D1_ + k];
        q[idx] = a;
    }
    __syncthreads();
    if (t < NC_ * NC_) {
        int i = t / NC_, j = t % NC_;
        float a = 0.f;
        for (int k = 0; k < D1_; k++) a += q[i * D1_ + k] * kh[j * D1_ + k];
        sc[t] = a * 0.1020620726159657f;     // 1/sqrt(96)
    }
    __syncthreads();
    if (t < NC_) {
        float m = sc[t * NC_];
        for (int j = 1; j < NC_; j++) m = fmaxf(m, sc[t * NC_ + j]);
        float e[NC_], s = 0.f;
        for (int j = 0; j < NC_; j++) { e[j] = __expf(sc[t * NC_ + j] - m); s += e[j]; }
        float inv = 1.f / s;
        for (int j = 0; j < NC_; j++) pp[t * NC_ + j] = e[j] * inv;
    }
    __syncthreads();
    for (int idx = t; idx < NC_ * C_; idx += 256) {
        int i = idx / C_, dv = idx % C_;
        float a = 0.f;
        for (int j = 0; j < NC_; j++) a += pp[i * NC_ + j] * vh[j * C_ + dv];
        o[idx] = a;
    }
    __syncthreads();
    for (int idx = t; idx < NC_ * C_; idx += 256) {
        int i = idx / C_, dd = idx % C_;
        float a = fcb[dd] + cs[idx];
        for (int c2 = 0; c2 < C_; c2++) a += o[i * C_ + c2] * fc[c2 * C_ + dd];
        z[idx] = a;
    }
    __syncthreads();
    if (t < NC_) {
        float s = 0.f;
        for (int d = 0; d < C_; d++) s += z[t * C_ + d];
        float mm = s / C_;
        float v = 0.f;
        for (int d = 0; d < C_; d++) { float dd2 = z[t * C_ + d] - mm; v += dd2 * dd2; }
        mu[t] = mm; rs[t] = rsqrtf(v / C_ + 1e-6f);
    }
    __syncthreads();
    for (int idx = t; idx < NC_ * C_; idx += 256) {
        int i = idx / C_, dd = idx % C_;
        cfs[(size_t)b * NC_ * C_ + idx] = (z[idx] - mu[i]) * rs[i] * lng[dd] + lnb[dd];
    }
}

// ---------------- K4: cf[b,hw,:] = sum_c weight1[b,hw,c] * cfs[b,c,:] ----------------
__global__ __launch_bounds__(256) void k4_redist(const float* __restrict__ w1,
                                                 const float* __restrict__ cfs,
                                                 float* __restrict__ cf) {
    int e = blockIdx.x * 256 + threadIdx.x;     // < 1048576
    int ch = e & 63, r = (e >> 6) & 1023, b = e >> 16;
    const float* wp = w1 + ((size_t)b * HW_ + r) * NC_;
    const float* cp = cfs + (size_t)b * NC_ * C_;
    float a = 0.f;
#pragma unroll
    for (int c2 = 0; c2 < NC_; c2++) a += wp[c2] * cp[c2 * C_ + ch];
    cf[e] = a;
}

// ---------------- K5: Q/K/V projections -> bf16 [b,h,l,64]; Q pre-scaled by log2e/8 ----------------
__global__ __launch_bounds__(256) void k5_proj(const float* __restrict__ cf,
                                               const float* __restrict__ wq, const float* __restrict__ bq,
                                               const float* __restrict__ wk, const float* __restrict__ bk,
                                               const float* __restrict__ wv, const float* __restrict__ bv,
                                               ushort_t* __restrict__ Qb, ushort_t* __restrict__ Kb,
                                               ushort_t* __restrict__ Vb) {
    __shared__ float rows[8][64];
    int t = threadIdx.x;
    int which = blockIdx.y;
    int m0 = blockIdx.x * 8;
    for (int e = t; e < 8 * 64; e += 256) rows[e >> 6][e & 63] = cf[(size_t)m0 * 64 + e];
    __syncthreads();
    const float* W = (which == 0) ? wq : (which == 1) ? wk : wv;
    const float* bias = (which == 0) ? bq : (which == 1) ? bk : bv;
    ushort_t* dst = (which == 0) ? Qb : (which == 1) ? Kb : Vb;
    // Q scale = (1/sqrt(64)) * log2(e): k6 uses exp2 directly (bare v_exp_f32)
    float scale = (which == 0) ? 0.18033688011112042f : 1.0f;
    int c = t;
    float bb = bias[c];
    float acc[8];
#pragma unroll
    for (int r = 0; r < 8; r++) acc[r] = bb;
    for (int k = 0; k < 64; k++) {
        float wv_ = W[k * 256 + c];
#pragma unroll
        for (int r = 0; r < 8; r++) acc[r] += rows[r][k] * wv_;
    }
    int h = c >> 6, dd = c & 63;
#pragma unroll
    for (int r = 0; r < 8; r++) {
        int m = m0 + r, b = m >> 10, hw = m & 1023;
        dst[(((size_t)(b * NH_ + h) * HW_) + hw) * DH_ + dd] = f2bf(acc[r] * scale);
    }
}

// ---------------- KT: Vt[b,h,d,l] = Vb[b,h,l,d] ----------------
__global__ __launch_bounds__(256) void kt_transpose(const ushort_t* __restrict__ Vb,
                                                    ushort_t* __restrict__ Vt) {
    __shared__ ushort_t tile[64][65];
    int t = threadIdx.x;
    int bh = blockIdx.y;
    int l0 = blockIdx.x * 64;
    const ushort_t* src = Vb + (size_t)bh * HW_ * DH_ + (size_t)l0 * DH_;
    for (int e = t; e < 4096; e += 256) { int l = e >> 6, d = e & 63; tile[d][l] = src[l * 64 + d]; }
    __syncthreads();
    ushort_t* dst = Vt + (size_t)bh * DH_ * HW_ + l0;
    for (int e = t; e < 4096; e += 256) { int d = e >> 6, l = e & 63; dst[(size_t)d * HW_ + l] = tile[d][l]; }
}

// ---------------- K6: MFMA bf16 flash attention v3 ----------------
// - 1 q-tile/wave, 1024 blocks (4/CU, 16 waves/CU): 2x TLP vs R5.
// - XCD swizzle: L%8 == bh%8 so all 16 q-blocks of a (b,h) share one XCD's L2 (K/V 2MB < 4MB).
// - no-max softmax (scores bounded), exp2 (Q pre-scaled by log2e/8), truncation bf16 pack.
// - softmax denominator via ones-fragment MFMA (sums the SAME bf16 P used in PV, over all
//   32 keys, zero shuffles).
// - explicit next-iter register prefetch (8 loads in flight across the compute).
__global__ __launch_bounds__(256, 4) void k6_attn(const ushort_t* __restrict__ Qb,
                                                  const ushort_t* __restrict__ Kb,
                                                  const ushort_t* __restrict__ Vt,
                                                  float* __restrict__ ao) {
    int t = threadIdx.x;
    int w = t >> 6;
    int lane = t & 63;
    int l15 = lane & 15;
    int quad = lane >> 4;
    // swizzled decode: block L -> (qt, bh) with L%8 == bh%8
    int L = blockIdx.x;
    int x8 = L & 7;
    int rest = L >> 3;          // qt*8 + bh_hi
    int qt = rest >> 3;         // 0..15
    int bh = (rest & 7) * 8 + x8;
    int b = bh >> 2, h = bh & 3;
    const ushort_t* Qp = Qb + (size_t)bh * HW_ * DH_;
    const ushort_t* Kp = Kb + (size_t)bh * HW_ * DH_;
    const ushort_t* Vp = Vt + (size_t)bh * DH_ * HW_;
    int row0 = qt * 64 + w * 16;
    short8 q0 = *(const short8*)(Qp + (size_t)(row0 + l15) * DH_ + quad * 8);
    short8 q1 = *(const short8*)(Qp + (size_t)(row0 + l15) * DH_ + 32 + quad * 8);
    // permuted key offsets: S^T tile0 row l15 -> key f0, tile1 -> f0+4
    int f0 = ((l15 >> 2) * 8) + (l15 & 3);
    const ushort_t* K0p = Kp + (size_t)f0 * DH_ + quad * 8;
    const ushort_t* K1p = Kp + (size_t)(f0 + 4) * DH_ + quad * 8;
    const ushort_t* Vp0 = Vp + (size_t)(0 * 16 + l15) * HW_ + quad * 8;
    const ushort_t* Vp1 = Vp + (size_t)(1 * 16 + l15) * HW_ + quad * 8;
    const ushort_t* Vp2 = Vp + (size_t)(2 * 16 + l15) * HW_ + quad * 8;
    const ushort_t* Vp3 = Vp + (size_t)(3 * 16 + l15) * HW_ + quad * 8;
    const short ONE = (short)0x3F80;      // bf16 1.0
    short8 ones = {ONE, ONE, ONE, ONE, ONE, ONE, ONE, ONE};
    f32x4 o0 = {0,0,0,0}, o1 = {0,0,0,0}, o2 = {0,0,0,0}, o3 = {0,0,0,0};
    f32x4 oS = {0,0,0,0};
    short8 ka0 = *(const short8*)(K0p);
    short8 ka1 = *(const short8*)(K0p + 32);
    short8 kb0 = *(const short8*)(K1p);
    short8 kb1 = *(const short8*)(K1p + 32);
    short8 v0 = *(const short8*)(Vp0);
    short8 v1 = *(const short8*)(Vp1);
    short8 v2 = *(const short8*)(Vp2);
    short8 v3 = *(const short8*)(Vp3);
    for (int kt = 0; kt < HW_ / 32; kt++) {
        int nk = (kt < 31) ? kt + 1 : 31;
        size_t koff = (size_t)nk * 32 * DH_;
        size_t voff = (size_t)nk * 32;
        short8 nka0 = *(const short8*)(K0p + koff);
        short8 nka1 = *(const short8*)(K0p + koff + 32);
        short8 nkb0 = *(const short8*)(K1p + koff);
        short8 nkb1 = *(const short8*)(K1p + koff + 32);
        short8 nv0 = *(const short8*)(Vp0 + voff);
        short8 nv1 = *(const short8*)(Vp1 + voff);
        short8 nv2 = *(const short8*)(Vp2 + voff);
        short8 nv3 = *(const short8*)(Vp3 + voff);
        f32x4 z = {0,0,0,0};
        f32x4 sT0 = MFMA32(ka0, q0, z);  sT0 = MFMA32(ka1, q1, sT0);
        f32x4 sT1 = MFMA32(kb0, q0, z);  sT1 = MFMA32(kb1, q1, sT1);
        float p0 = exp2f(sT0[0]), p1 = exp2f(sT0[1]);
        float p2 = exp2f(sT0[2]), p3 = exp2f(sT0[3]);
        float p4 = exp2f(sT1[0]), p5 = exp2f(sT1[1]);
        float p6 = exp2f(sT1[2]), p7 = exp2f(sT1[3]);
        union { short8 v; unsigned u[4]; } pf;
        pf.u[0] = pack2_trunc(p0, p1);
        pf.u[1] = pack2_trunc(p2, p3);
        pf.u[2] = pack2_trunc(p4, p5);
        pf.u[3] = pack2_trunc(p6, p7);
        o0 = MFMA32(v0, pf.v, o0);
        o1 = MFMA32(v1, pf.v, o1);
        o2 = MFMA32(v2, pf.v, o2);
        o3 = MFMA32(v3, pf.v, o3);
        oS = MFMA32(ones, pf.v, oS);     // denominator: sum over all 32 keys of bf16 P
        ka0 = nka0; ka1 = nka1; kb0 = nkb0; kb1 = nkb1;
        v0 = nv0; v1 = nv1; v2 = nv2; v3 = nv3;
    }
    float inv = 1.f / oS[0];             // per-lane column q = l15 (all 4 regs equal)
    int rowg = row0 + l15;
    float* aop = ao + ((size_t)(b * HW_ + rowg)) * (NH_ * DH_) + h * DH_ + quad * 4;
    float4 r0 = {o0[0] * inv, o0[1] * inv, o0[2] * inv, o0[3] * inv};
    float4 r1 = {o1[0] * inv, o1[1] * inv, o1[2] * inv, o1[3] * inv};
    float4 r2 = {o2[0] * inv, o2[1] * inv, o2[2] * inv, o2[3] * inv};
    float4 r3 = {o3[0] * inv, o3[1] * inv, o3[2] * inv, o3[3] * inv};
    *(float4*)(aop + 0)  = r0;
    *(float4*)(aop + 16) = r1;
    *(float4*)(aop + 32) = r2;
    *(float4*)(aop + 48) = r3;
}

// ---------------- K7: out = LN(ao @ fc + fcb + cf) -> transposed [b,64,32,32] ----------------
// 16 rows/block (grid 1024): fc L2 traffic /4, each fc load feeds 4 FMAs; full-line stores.
__global__ __launch_bounds__(256) void k7_final(const float* __restrict__ ao,
                                                const float* __restrict__ fc, const float* __restrict__ fcb,
                                                const float* __restrict__ cf,
                                                const float* __restrict__ lng, const float* __restrict__ lnb,
                                                float* __restrict__ out) {
    __shared__ float srow[16 * 256];      // 16 KB
    __shared__ float T[64 * 17];          // padded transpose buffer
    int t = threadIdx.x, w = t >> 6, d = t & 63;
    int m0 = blockIdx.x * 16;
    for (int i = t; i < 1024; i += 256)
        *(float4*)&srow[i * 4] = *(const float4*)&ao[(size_t)m0 * 256 + i * 4];
    __syncthreads();
    float bias = fcb[d];
    float a[4];
#pragma unroll
    for (int j = 0; j < 4; j++)
        a[j] = bias + cf[(size_t)(m0 + w * 4 + j) * 64 + d];
    for (int k = 0; k < 256; k++) {
        float f = fc[k * 64 + d];
#pragma unroll
        for (int j = 0; j < 4; j++) a[j] += srow[(w * 4 + j) * 256 + k] * f;
    }
    float g = lng[d], be = lnb[d];
#pragma unroll
    for (int j = 0; j < 4; j++) {
        float s1 = a[j], s2 = a[j] * a[j];
#pragma unroll
        for (int off = 1; off < 64; off <<= 1) {
            s1 += __shfl_xor(s1, off, 64);
            s2 += __shfl_xor(s2, off, 64);
        }
        float mu = s1 * (1.f / 64.f);
        float var = s2 * (1.f / 64.f) - mu * mu;
        float rstd = rsqrtf(var + 1e-6f);
        T[d * 17 + w * 4 + j] = (a[j] - mu) * rstd * g + be;
    }
    __syncthreads();
    int ch = t >> 2, part = t & 3;
    int b = m0 >> 10, hw0 = m0 & 1023;
    float4 v = {T[ch * 17 + part * 4 + 0], T[ch * 17 + part * 4 + 1],
                T[ch * 17 + part * 4 + 2], T[ch * 17 + part * 4 + 3]};
    *(float4*)&out[((size_t)b * 64 + ch) * 1024 + hw0 + part * 4] = v;
}

// ---------------- launcher ----------------
extern "C" void kernel_launch(void* const* d_in, const int* in_sizes, int n_in,
                              void* d_out, int out_size, void* d_ws, size_t ws_size,
                              hipStream_t stream) {
    const float* x      = (const float*)d_in[0];
    const float* memory = (const float*)d_in[1];
    const float* wb_w   = (const float*)d_in[2];
    const float* wb_b   = (const float*)d_in[3];
    const float* a1_wq  = (const float*)d_in[4];
    const float* a1_bq  = (const float*)d_in[5];
    const float* a1_wk  = (const float*)d_in[6];
    const float* a1_bk  = (const float*)d_in[7];
    const float* a1_wv  = (const float*)d_in[8];
    const float* a1_bv  = (const float*)d_in[9];
    const float* a1_fc  = (const float*)d_in[10];
    const float* a1_fcb = (const float*)d_in[11];
    const float* a1_ln_g = (const float*)d_in[12];
    const float* a1_ln_b = (const float*)d_in[13];
    const float* a2_wq  = (const float*)d_in[14];
    const float* a2_bq  = (const float*)d_in[15];
    const float* a2_wk  = (const float*)d_in[16];
    const float* a2_bk  = (const float*)d_in[17];
    const float* a2_wv  = (const float*)d_in[18];
    const float* a2_bv  = (const float*)d_in[19];
    const float* a2_fc  = (const float*)d_in[20];
    const float* a2_fcb = (const float*)d_in[21];
    const float* a2_ln_g = (const float*)d_in[22];
    const float* a2_ln_b = (const float*)d_in[23];

    float* ws = (float*)d_ws;
    float* logitsT = ws;                                   // 16*5*1024
    float* w2buf = logitsT + 16 * 5 * 1024;                // 16*5*1024
    float* w1  = w2buf + 16 * 5 * 1024;                    // 16*1024*5
    float* cf1 = w1 + 16 * 1024 * 5;                       // 16*5*64
    float* cfs = cf1 + 16 * 5 * 64;                        // 16*5*64
    float* cf  = cfs + 16 * 5 * 64;                        // 16*1024*64
    float* ao  = cf + 16 * 1024 * 64;                      // 16*1024*256
    ushort_t* Qb = (ushort_t*)(ao + 16 * 1024 * 256);      // 16*4*1024*64 bf16
    ushort_t* Kb = Qb + 16 * 4 * 1024 * 64;
    ushort_t* Vb = Kb + 16 * 4 * 1024 * 64;
    ushort_t* Vt = Vb + 16 * 4 * 1024 * 64;

    k1_logits<<<256, 64, 0, stream>>>(x, wb_w, wb_b, logitsT, w1);
    k2a_softmax<<<80, 256, 0, stream>>>(logitsT, w2buf);
    k2b_pool<<<256, 256, 0, stream>>>(x, w2buf, cf1);
    k3_mha1<<<16, 256, 0, stream>>>(cf1, a1_wq, a1_bq, memory, a1_wk, a1_bk,
                                    a1_wv, a1_bv, a1_fc, a1_fcb,
                                    a1_ln_g, a1_ln_b, cfs);
    k4_redist<<<4096, 256, 0, stream>>>(w1, cfs, cf);
    k5_proj<<<dim3(2048, 3), 256, 0, stream>>>(cf, a2_wq, a2_bq, a2_wk, a2_bk,
                                               a2_wv, a2_bv, Qb, Kb, Vb);
    kt_transpose<<<dim3(16, 64), 256, 0, stream>>>(Vb, Vt);
    k6_attn<<<1024, 256, 0, stream>>>(Qb, Kb, Vt, ao);
    k7_final<<<1024, 256, 0, stream>>>(ao, a2_fc, a2_fcb, cf, a2_ln_g, a2_ln_b,
                                       (float*)d_out);
}

// Round 7
// 305.611 us; speedup vs baseline: 1.0007x; 1.0007x over previous
//
#include <hip/hip_runtime.h>
#include <math.h>

typedef unsigned short ushort_t;
typedef __attribute__((ext_vector_type(8))) short short8;
typedef __attribute__((ext_vector_type(4))) float f32x4;

#define B_  16
#define HW_ 1024
#define C_  64
#define NC_ 5
#define D1_ 96
#define NH_ 4
#define DH_ 64

#define MFMA32(A,B,C) __builtin_amdgcn_mfma_f32_16x16x32_bf16(A,B,C,0,0,0)

__device__ __forceinline__ ushort_t f2bf(float f) {
    unsigned u = __float_as_uint(f);
    u = u + 0x7fffu + ((u >> 16) & 1u);   // round-to-nearest-even
    return (ushort_t)(u >> 16);
}

// truncating bf16 pair-pack: one op per 2 elements
__device__ __forceinline__ unsigned pack2_trunc(float lo, float hi) {
    return (__float_as_uint(hi) & 0xffff0000u) | (__float_as_uint(lo) >> 16);
}

// ---------------- K1: logits = xt @ wb_w + wb_b ; weight1 = softmax over classes ----------------
__global__ __launch_bounds__(64) void k1_logits(const float* __restrict__ x,
                                                const float* __restrict__ wb_w,
                                                const float* __restrict__ wb_b,
                                                float* __restrict__ logitsT,
                                                float* __restrict__ w1) {
    int b = blockIdx.x >> 4;
    int hw = (blockIdx.x & 15) * 64 + threadIdx.x;
    const float* xb = x + (size_t)b * C_ * HW_;
    float acc[NC_];
#pragma unroll
    for (int j = 0; j < NC_; j++) acc[j] = wb_b[j];
#pragma unroll 8
    for (int c = 0; c < C_; c++) {
        float xv = xb[c * HW_ + hw];
#pragma unroll
        for (int j = 0; j < NC_; j++) acc[j] += xv * wb_w[c * NC_ + j];
    }
    float m = acc[0];
#pragma unroll
    for (int j = 1; j < NC_; j++) m = fmaxf(m, acc[j]);
    float e[NC_], s = 0.f;
#pragma unroll
    for (int j = 0; j < NC_; j++) { e[j] = __expf(acc[j] - m); s += e[j]; }
    float inv = 1.f / s;
    int idx = b * HW_ + hw;
#pragma unroll
    for (int j = 0; j < NC_; j++) {
        logitsT[((size_t)b * NC_ + j) * HW_ + hw] = acc[j];
        w1[(size_t)idx * NC_ + j] = e[j] * inv;
    }
}

// ---------------- K2a: w2[b,c,:] = softmax over HW of logitsT[b,c,:] ----------------
__global__ __launch_bounds__(256) void k2a_softmax(const float* __restrict__ logitsT,
                                                   float* __restrict__ w2) {
    __shared__ float red[256];
    int t = threadIdx.x;
    const float* lp = logitsT + (size_t)blockIdx.x * HW_;
    float* wp = w2 + (size_t)blockIdx.x * HW_;
    float4 v = *(const float4*)(lp + t * 4);
    float lm = fmaxf(fmaxf(v.x, v.y), fmaxf(v.z, v.w));
#pragma unroll
    for (int off = 1; off < 64; off <<= 1) lm = fmaxf(lm, __shfl_xor(lm, off, 64));
    if ((t & 63) == 0) red[t >> 6] = lm;
    __syncthreads();
    float m = fmaxf(fmaxf(red[0], red[1]), fmaxf(red[2], red[3]));
    float e0 = __expf(v.x - m), e1 = __expf(v.y - m);
    float e2 = __expf(v.z - m), e3 = __expf(v.w - m);
    float ls = (e0 + e1) + (e2 + e3);
#pragma unroll
    for (int off = 1; off < 64; off <<= 1) ls += __shfl_xor(ls, off, 64);
    __syncthreads();
    if ((t & 63) == 0) red[t >> 6] = ls;
    __syncthreads();
    float inv = 1.f / (((red[0] + red[1]) + (red[2] + red[3])));
    float4 o = {e0 * inv, e1 * inv, e2 * inv, e3 * inv};
    *(float4*)(wp + t * 4) = o;
}

// ---------------- K2b: cf1[b,c,ch] = sum_hw w2[b,c,hw] * x[b,ch,hw] ----------------
__global__ __launch_bounds__(256) void k2b_pool(const float* __restrict__ x,
                                                const float* __restrict__ w2,
                                                float* __restrict__ cf1) {
    __shared__ float pl[NC_ * HW_];     // 20 KB
    int t = threadIdx.x;
    int b = blockIdx.x >> 4, chg = blockIdx.x & 15;
    const float* wb = w2 + (size_t)b * NC_ * HW_;
    for (int i = t; i < NC_ * HW_ / 4; i += 256)
        *(float4*)(pl + i * 4) = *(const float4*)(wb + i * 4);
    __syncthreads();
    int w = t >> 6, lane = t & 63;
    int ch = chg * 4 + w;
    const float* xc = x + ((size_t)b * C_ + ch) * HW_;
    float acc[NC_] = {0.f, 0.f, 0.f, 0.f, 0.f};
#pragma unroll
    for (int i = 0; i < HW_ / 64; i++) {
        int hw = i * 64 + lane;
        float xv = xc[hw];
#pragma unroll
        for (int c = 0; c < NC_; c++) acc[c] += xv * pl[c * HW_ + hw];
    }
#pragma unroll
    for (int c = 0; c < NC_; c++) {
        float a = acc[c];
#pragma unroll
        for (int off = 1; off < 64; off <<= 1) a += __shfl_xor(a, off, 64);
        if (lane == 0) cf1[((size_t)b * NC_ + c) * C_ + ch] = a;
    }
}

// ---------------- K3: MHA1 (n_head=1, dk=96, dv=64) + residual + LN, per batch ----------------
__global__ __launch_bounds__(256) void k3_mha1(const float* __restrict__ cf1,
                                               const float* __restrict__ wq, const float* __restrict__ bq,
                                               const float* __restrict__ mem,
                                               const float* __restrict__ wk, const float* __restrict__ bk,
                                               const float* __restrict__ wv, const float* __restrict__ bv,
                                               const float* __restrict__ fc, const float* __restrict__ fcb,
                                               const float* __restrict__ lng, const float* __restrict__ lnb,
                                               float* __restrict__ cfs) {
    __shared__ float cs[NC_ * C_];
    __shared__ float kh[NC_ * D1_];
    __shared__ float vh[NC_ * DH_];
    __shared__ float q[NC_ * D1_];
    __shared__ float sc[NC_ * NC_];
    __shared__ float pp[NC_ * NC_];
    __shared__ float o[NC_ * C_];
    __shared__ float z[NC_ * C_];
    __shared__ float mu[NC_], rs[NC_];
    int t = threadIdx.x, b = blockIdx.x;
    for (int i = t; i < NC_ * C_; i += 256) cs[i] = cf1[(size_t)b * NC_ * C_ + i];
    for (int idx = t; idx < NC_ * D1_; idx += 256) {
        int i = idx / D1_, k = idx % D1_;
        float a = bk[k];
        for (int d = 0; d < D1_; d++) a += mem[i * D1_ + d] * wk[d * D1_ + k];
        kh[idx] = a;
    }
    for (int idx = t; idx < NC_ * DH_; idx += 256) {
        int i = idx / DH_, dv = idx % DH_;
        float a = bv[dv];
        for (int d = 0; d < D1_; d++) a += mem[i * D1_ + d] * wv[d * DH_ + dv];
        vh[idx] = a;
    }
    __syncthreads();
    for (int idx = t; idx < NC_ * D1_; idx += 256) {
        int i = idx / D1_, k = idx % D1_;
        float a = bq[k];
        for (int c = 0; c < C_; c++) a += cs[i * C_ + c] * wq[c * D1_ + k];
        q[idx] = a;
    }
    __syncthreads();
    if (t < NC_ * NC_) {
        int i = t / NC_, j = t % NC_;
        float a = 0.f;
        for (int k = 0; k < D1_; k++) a += q[i * D1_ + k] * kh[j * D1_ + k];
        sc[t] = a * 0.1020620726159657f;     // 1/sqrt(96)
    }
    __syncthreads();
    if (t < NC_) {
        float m = sc[t * NC_];
        for (int j = 1; j < NC_; j++) m = fmaxf(m, sc[t * NC_ + j]);
        float e[NC_], s = 0.f;
        for (int j = 0; j < NC_; j++) { e[j] = __expf(sc[t * NC_ + j] - m); s += e[j]; }
        float inv = 1.f / s;
        for (int j = 0; j < NC_; j++) pp[t * NC_ + j] = e[j] * inv;
    }
    __syncthreads();
    for (int idx = t; idx < NC_ * C_; idx += 256) {
        int i = idx / C_, dv = idx % C_;
        float a = 0.f;
        for (int j = 0; j < NC_; j++) a += pp[i * NC_ + j] * vh[j * C_ + dv];
        o[idx] = a;
    }
    __syncthreads();
    for (int idx = t; idx < NC_ * C_; idx += 256) {
        int i = idx / C_, dd = idx % C_;
        float a = fcb[dd] + cs[idx];
        for (int c2 = 0; c2 < C_; c2++) a += o[i * C_ + c2] * fc[c2 * C_ + dd];
        z[idx] = a;
    }
    __syncthreads();
    if (t < NC_) {
        float s = 0.f;
        for (int d = 0; d < C_; d++) s += z[t * C_ + d];
        float mm = s / C_;
        float v = 0.f;
        for (int d = 0; d < C_; d++) { float dd2 = z[t * C_ + d] - mm; v += dd2 * dd2; }
        mu[t] = mm; rs[t] = rsqrtf(v / C_ + 1e-6f);
    }
    __syncthreads();
    for (int idx = t; idx < NC_ * C_; idx += 256) {
        int i = idx / C_, dd = idx % C_;
        cfs[(size_t)b * NC_ * C_ + idx] = (z[idx] - mu[i]) * rs[i] * lng[dd] + lnb[dd];
    }
}

// ---------------- K4: cf[b,hw,:] = sum_c weight1[b,hw,c] * cfs[b,c,:] ----------------
__global__ __launch_bounds__(256) void k4_redist(const float* __restrict__ w1,
                                                 const float* __restrict__ cfs,
                                                 float* __restrict__ cf) {
    int e = blockIdx.x * 256 + threadIdx.x;     // < 1048576
    int ch = e & 63, r = (e >> 6) & 1023, b = e >> 16;
    const float* wp = w1 + ((size_t)b * HW_ + r) * NC_;
    const float* cp = cfs + (size_t)b * NC_ * C_;
    float a = 0.f;
#pragma unroll
    for (int c2 = 0; c2 < NC_; c2++) a += wp[c2] * cp[c2 * C_ + ch];
    cf[e] = a;
}

// ---------------- K5: Q/K/V projections -> bf16 [b,h,l,64]; Q pre-scaled by log2e/8 ----------------
__global__ __launch_bounds__(256) void k5_proj(const float* __restrict__ cf,
                                               const float* __restrict__ wq, const float* __restrict__ bq,
                                               const float* __restrict__ wk, const float* __restrict__ bk,
                                               const float* __restrict__ wv, const float* __restrict__ bv,
                                               ushort_t* __restrict__ Qb, ushort_t* __restrict__ Kb,
                                               ushort_t* __restrict__ Vb) {
    __shared__ float rows[8][64];
    int t = threadIdx.x;
    int which = blockIdx.y;
    int m0 = blockIdx.x * 8;
    for (int e = t; e < 8 * 64; e += 256) rows[e >> 6][e & 63] = cf[(size_t)m0 * 64 + e];
    __syncthreads();
    const float* W = (which == 0) ? wq : (which == 1) ? wk : wv;
    const float* bias = (which == 0) ? bq : (which == 1) ? bk : bv;
    ushort_t* dst = (which == 0) ? Qb : (which == 1) ? Kb : Vb;
    // Q scale = (1/sqrt(64)) * log2(e): k6 uses exp2 directly (bare v_exp_f32)
    float scale = (which == 0) ? 0.18033688011112042f : 1.0f;
    int c = t;
    float bb = bias[c];
    float acc[8];
#pragma unroll
    for (int r = 0; r < 8; r++) acc[r] = bb;
    for (int k = 0; k < 64; k++) {
        float wv_ = W[k * 256 + c];
#pragma unroll
        for (int r = 0; r < 8; r++) acc[r] += rows[r][k] * wv_;
    }
    int h = c >> 6, dd = c & 63;
#pragma unroll
    for (int r = 0; r < 8; r++) {
        int m = m0 + r, b = m >> 10, hw = m & 1023;
        dst[(((size_t)(b * NH_ + h) * HW_) + hw) * DH_ + dd] = f2bf(acc[r] * scale);
    }
}

// ---------------- KT: Vt[b,h,d,l] = Vb[b,h,l,d] ----------------
__global__ __launch_bounds__(256) void kt_transpose(const ushort_t* __restrict__ Vb,
                                                    ushort_t* __restrict__ Vt) {
    __shared__ ushort_t tile[64][65];
    int t = threadIdx.x;
    int bh = blockIdx.y;
    int l0 = blockIdx.x * 64;
    const ushort_t* src = Vb + (size_t)bh * HW_ * DH_ + (size_t)l0 * DH_;
    for (int e = t; e < 4096; e += 256) { int l = e >> 6, d = e & 63; tile[d][l] = src[l * 64 + d]; }
    __syncthreads();
    ushort_t* dst = Vt + (size_t)bh * DH_ * HW_ + l0;
    for (int e = t; e < 4096; e += 256) { int d = e >> 6, l = e & 63; dst[(size_t)d * HW_ + l] = tile[d][l]; }
}

// ---------------- K6: MFMA bf16 flash attention v4 ----------------
// - 1 q-tile/wave, grid 1024 (4 blocks/CU) for TLP; XCD swizzle (L%8==bh%8) keeps each
//   (b,h)'s K/V in one XCD's L2 (12 MB total HBM fetch, measured R6).
// - NO launch_bounds cap, NO manual prefetch (R6 lesson: reg-cap + prefetch => compiler
//   serializes VMEM, 2x regression). Compiler schedules loads at VGPR ~80.
// - no-max softmax (scores bounded), exp2 (Q pre-scaled by log2e/8), trunc bf16 pack,
//   denominator via ones-fragment MFMA.
// - unroll 2: PV(i) overlaps S(i+1) (disjoint accumulators).
__global__ __launch_bounds__(256) void k6_attn(const ushort_t* __restrict__ Qb,
                                               const ushort_t* __restrict__ Kb,
                                               const ushort_t* __restrict__ Vt,
                                               float* __restrict__ ao) {
    int t = threadIdx.x;
    int w = t >> 6;
    int lane = t & 63;
    int l15 = lane & 15;
    int quad = lane >> 4;
    // swizzled decode: block L -> (qt, bh) with L%8 == bh%8
    int L = blockIdx.x;
    int x8 = L & 7;
    int rest = L >> 3;          // qt*8 + bh_hi
    int qt = rest >> 3;         // 0..15
    int bh = (rest & 7) * 8 + x8;
    int b = bh >> 2, h = bh & 3;
    const ushort_t* Qp = Qb + (size_t)bh * HW_ * DH_;
    const ushort_t* Kp = Kb + (size_t)bh * HW_ * DH_;
    const ushort_t* Vp = Vt + (size_t)bh * DH_ * HW_;
    int row0 = qt * 64 + w * 16;
    short8 q0 = *(const short8*)(Qp + (size_t)(row0 + l15) * DH_ + quad * 8);
    short8 q1 = *(const short8*)(Qp + (size_t)(row0 + l15) * DH_ + 32 + quad * 8);
    // permuted key offsets: S^T tile0 row l15 -> key f0, tile1 -> f0+4
    int f0 = ((l15 >> 2) * 8) + (l15 & 3);
    const ushort_t* K0p = Kp + (size_t)f0 * DH_ + quad * 8;
    const ushort_t* K1p = Kp + (size_t)(f0 + 4) * DH_ + quad * 8;
    const ushort_t* Vp0 = Vp + (size_t)(0 * 16 + l15) * HW_ + quad * 8;
    const ushort_t* Vp1 = Vp + (size_t)(1 * 16 + l15) * HW_ + quad * 8;
    const ushort_t* Vp2 = Vp + (size_t)(2 * 16 + l15) * HW_ + quad * 8;
    const ushort_t* Vp3 = Vp + (size_t)(3 * 16 + l15) * HW_ + quad * 8;
    const short ONE = (short)0x3F80;      // bf16 1.0
    short8 ones = {ONE, ONE, ONE, ONE, ONE, ONE, ONE, ONE};
    f32x4 o0 = {0,0,0,0}, o1 = {0,0,0,0}, o2 = {0,0,0,0}, o3 = {0,0,0,0};
    f32x4 oS = {0,0,0,0};
#pragma unroll 2
    for (int kt = 0; kt < HW_ / 32; kt++) {
        int kbase = kt * 32;
        size_t koff = (size_t)kbase * DH_;
        short8 ka0 = *(const short8*)(K0p + koff);
        short8 ka1 = *(const short8*)(K0p + koff + 32);
        short8 kb0 = *(const short8*)(K1p + koff);
        short8 kb1 = *(const short8*)(K1p + koff + 32);
        short8 v0 = *(const short8*)(Vp0 + kbase);
        short8 v1 = *(const short8*)(Vp1 + kbase);
        short8 v2 = *(const short8*)(Vp2 + kbase);
        short8 v3 = *(const short8*)(Vp3 + kbase);
        f32x4 z = {0,0,0,0};
        f32x4 sT0 = MFMA32(ka0, q0, z);  sT0 = MFMA32(ka1, q1, sT0);
        f32x4 sT1 = MFMA32(kb0, q0, z);  sT1 = MFMA32(kb1, q1, sT1);
        float p0 = exp2f(sT0[0]), p1 = exp2f(sT0[1]);
        float p2 = exp2f(sT0[2]), p3 = exp2f(sT0[3]);
        float p4 = exp2f(sT1[0]), p5 = exp2f(sT1[1]);
        float p6 = exp2f(sT1[2]), p7 = exp2f(sT1[3]);
        union { short8 v; unsigned u[4]; } pf;
        pf.u[0] = pack2_trunc(p0, p1);
        pf.u[1] = pack2_trunc(p2, p3);
        pf.u[2] = pack2_trunc(p4, p5);
        pf.u[3] = pack2_trunc(p6, p7);
        o0 = MFMA32(v0, pf.v, o0);
        o1 = MFMA32(v1, pf.v, o1);
        o2 = MFMA32(v2, pf.v, o2);
        o3 = MFMA32(v3, pf.v, o3);
        oS = MFMA32(ones, pf.v, oS);     // denominator: sum over all 32 keys of bf16 P
    }
    float inv = 1.f / oS[0];             // per-lane column q = l15 (all 4 regs equal)
    int rowg = row0 + l15;
    float* aop = ao + ((size_t)(b * HW_ + rowg)) * (NH_ * DH_) + h * DH_ + quad * 4;
    float4 r0 = {o0[0] * inv, o0[1] * inv, o0[2] * inv, o0[3] * inv};
    float4 r1 = {o1[0] * inv, o1[1] * inv, o1[2] * inv, o1[3] * inv};
    float4 r2 = {o2[0] * inv, o2[1] * inv, o2[2] * inv, o2[3] * inv};
    float4 r3 = {o3[0] * inv, o3[1] * inv, o3[2] * inv, o3[3] * inv};
    *(float4*)(aop + 0)  = r0;
    *(float4*)(aop + 16) = r1;
    *(float4*)(aop + 32) = r2;
    *(float4*)(aop + 48) = r3;
}

// ---------------- K7: out = LN(ao @ fc + fcb + cf) -> transposed [b,64,32,32] ----------------
__global__ __launch_bounds__(256) void k7_final(const float* __restrict__ ao,
                                                const float* __restrict__ fc, const float* __restrict__ fcb,
                                                const float* __restrict__ cf,
                                                const float* __restrict__ lng, const float* __restrict__ lnb,
                                                float* __restrict__ out) {
    __shared__ float srow[16 * 256];      // 16 KB
    __shared__ float T[64 * 17];          // padded transpose buffer
    int t = threadIdx.x, w = t >> 6, d = t & 63;
    int m0 = blockIdx.x * 16;
    for (int i = t; i < 1024; i += 256)
        *(float4*)&srow[i * 4] = *(const float4*)&ao[(size_t)m0 * 256 + i * 4];
    __syncthreads();
    float bias = fcb[d];
    float a[4];
#pragma unroll
    for (int j = 0; j < 4; j++)
        a[j] = bias + cf[(size_t)(m0 + w * 4 + j) * 64 + d];
    for (int k = 0; k < 256; k++) {
        float f = fc[k * 64 + d];
#pragma unroll
        for (int j = 0; j < 4; j++) a[j] += srow[(w * 4 + j) * 256 + k] * f;
    }
    float g = lng[d], be = lnb[d];
#pragma unroll
    for (int j = 0; j < 4; j++) {
        float s1 = a[j], s2 = a[j] * a[j];
#pragma unroll
        for (int off = 1; off < 64; off <<= 1) {
            s1 += __shfl_xor(s1, off, 64);
            s2 += __shfl_xor(s2, off, 64);
        }
        float mu = s1 * (1.f / 64.f);
        float var = s2 * (1.f / 64.f) - mu * mu;
        float rstd = rsqrtf(var + 1e-6f);
        T[d * 17 + w * 4 + j] = (a[j] - mu) * rstd * g + be;
    }
    __syncthreads();
    int ch = t >> 2, part = t & 3;
    int b = m0 >> 10, hw0 = m0 & 1023;
    float4 v = {T[ch * 17 + part * 4 + 0], T[ch * 17 + part * 4 + 1],
                T[ch * 17 + part * 4 + 2], T[ch * 17 + part * 4 + 3]};
    *(float4*)&out[((size_t)b * 64 + ch) * 1024 + hw0 + part * 4] = v;
}

// ---------------- launcher ----------------
extern "C" void kernel_launch(void* const* d_in, const int* in_sizes, int n_in,
                              void* d_out, int out_size, void* d_ws, size_t ws_size,
                              hipStream_t stream) {
    const float* x      = (const float*)d_in[0];
    const float* memory = (const float*)d_in[1];
    const float* wb_w   = (const float*)d_in[2];
    const float* wb_b   = (const float*)d_in[3];
    const float* a1_wq  = (const float*)d_in[4];
    const float* a1_bq  = (const float*)d_in[5];
    const float* a1_wk  = (const float*)d_in[6];
    const float* a1_bk  = (const float*)d_in[7];
    const float* a1_wv  = (const float*)d_in[8];
    const float* a1_bv  = (const float*)d_in[9];
    const float* a1_fc  = (const float*)d_in[10];
    const float* a1_fcb = (const float*)d_in[11];
    const float* a1_ln_g = (const float*)d_in[12];
    const float* a1_ln_b = (const float*)d_in[13];
    const float* a2_wq  = (const float*)d_in[14];
    const float* a2_bq  = (const float*)d_in[15];
    const float* a2_wk  = (const float*)d_in[16];
    const float* a2_bk  = (const float*)d_in[17];
    const float* a2_wv  = (const float*)d_in[18];
    const float* a2_bv  = (const float*)d_in[19];
    const float* a2_fc  = (const float*)d_in[20];
    const float* a2_fcb = (const float*)d_in[21];
    const float* a2_ln_g = (const float*)d_in[22];
    const float* a2_ln_b = (const float*)d_in[23];

    float* ws = (float*)d_ws;
    float* logitsT = ws;                                   // 16*5*1024
    float* w2buf = logitsT + 16 * 5 * 1024;                // 16*5*1024
    float* w1  = w2buf + 16 * 5 * 1024;                    // 16*1024*5
    float* cf1 = w1 + 16 * 1024 * 5;                       // 16*5*64
    float* cfs = cf1 + 16 * 5 * 64;                        // 16*5*64
    float* cf  = cfs + 16 * 5 * 64;                        // 16*1024*64
    float* ao  = cf + 16 * 1024 * 64;                      // 16*1024*256
    ushort_t* Qb = (ushort_t*)(ao + 16 * 1024 * 256);      // 16*4*1024*64 bf16
    ushort_t* Kb = Qb + 16 * 4 * 1024 * 64;
    ushort_t* Vb = Kb + 16 * 4 * 1024 * 64;
    ushort_t* Vt = Vb + 16 * 4 * 1024 * 64;

    k1_logits<<<256, 64, 0, stream>>>(x, wb_w, wb_b, logitsT, w1);
    k2a_softmax<<<80, 256, 0, stream>>>(logitsT, w2buf);
    k2b_pool<<<256, 256, 0, stream>>>(x, w2buf, cf1);
    k3_mha1<<<16, 256, 0, stream>>>(cf1, a1_wq, a1_bq, memory, a1_wk, a1_bk,
                                    a1_wv, a1_bv, a1_fc, a1_fcb,
                                    a1_ln_g, a1_ln_b, cfs);
    k4_redist<<<4096, 256, 0, stream>>>(w1, cfs, cf);
    k5_proj<<<dim3(2048, 3), 256, 0, stream>>>(cf, a2_wq, a2_bq, a2_wk, a2_bk,
                                               a2_wv, a2_bv, Qb, Kb, Vb);
    kt_transpose<<<dim3(16, 64), 256, 0, stream>>>(Vb, Vt);
    k6_attn<<<1024, 256, 0, stream>>>(Qb, Kb, Vt, ao);
    k7_final<<<1024, 256, 0, stream>>>(ao, a2_fc, a2_fcb, cf, a2_ln_g, a2_ln_b,
                                       (float*)d_out);
}

// Round 8
// 260.380 us; speedup vs baseline: 1.1746x; 1.1737x over previous
//
#include <hip/hip_runtime.h>
#include <math.h>

typedef unsigned short ushort_t;
typedef __attribute__((ext_vector_type(8))) short short8;
typedef __attribute__((ext_vector_type(4))) float f32x4;

#define B_  16
#define HW_ 1024
#define C_  64
#define NC_ 5
#define D1_ 96
#define NH_ 4
#define DH_ 64

#define MFMA32(A,B,C) __builtin_amdgcn_mfma_f32_16x16x32_bf16(A,B,C,0,0,0)

__device__ __forceinline__ ushort_t f2bf(float f) {
    unsigned u = __float_as_uint(f);
    u = u + 0x7fffu + ((u >> 16) & 1u);   // round-to-nearest-even
    return (ushort_t)(u >> 16);
}

// truncating bf16 pair-pack: one op per 2 elements
__device__ __forceinline__ unsigned pack2_trunc(float lo, float hi) {
    return (__float_as_uint(hi) & 0xffff0000u) | (__float_as_uint(lo) >> 16);
}

// ---------------- K1: logits = xt @ wb_w + wb_b ; weight1 = softmax over classes ----------------
__global__ __launch_bounds__(64) void k1_logits(const float* __restrict__ x,
                                                const float* __restrict__ wb_w,
                                                const float* __restrict__ wb_b,
                                                float* __restrict__ logitsT,
                                                float* __restrict__ w1) {
    int b = blockIdx.x >> 4;
    int hw = (blockIdx.x & 15) * 64 + threadIdx.x;
    const float* xb = x + (size_t)b * C_ * HW_;
    float acc[NC_];
#pragma unroll
    for (int j = 0; j < NC_; j++) acc[j] = wb_b[j];
#pragma unroll 8
    for (int c = 0; c < C_; c++) {
        float xv = xb[c * HW_ + hw];
#pragma unroll
        for (int j = 0; j < NC_; j++) acc[j] += xv * wb_w[c * NC_ + j];
    }
    float m = acc[0];
#pragma unroll
    for (int j = 1; j < NC_; j++) m = fmaxf(m, acc[j]);
    float e[NC_], s = 0.f;
#pragma unroll
    for (int j = 0; j < NC_; j++) { e[j] = __expf(acc[j] - m); s += e[j]; }
    float inv = 1.f / s;
    int idx = b * HW_ + hw;
#pragma unroll
    for (int j = 0; j < NC_; j++) {
        logitsT[((size_t)b * NC_ + j) * HW_ + hw] = acc[j];
        w1[(size_t)idx * NC_ + j] = e[j] * inv;
    }
}

// ---------------- K2a: w2[b,c,:] = softmax over HW of logitsT[b,c,:] ----------------
__global__ __launch_bounds__(256) void k2a_softmax(const float* __restrict__ logitsT,
                                                   float* __restrict__ w2) {
    __shared__ float red[256];
    int t = threadIdx.x;
    const float* lp = logitsT + (size_t)blockIdx.x * HW_;
    float* wp = w2 + (size_t)blockIdx.x * HW_;
    float4 v = *(const float4*)(lp + t * 4);
    float lm = fmaxf(fmaxf(v.x, v.y), fmaxf(v.z, v.w));
#pragma unroll
    for (int off = 1; off < 64; off <<= 1) lm = fmaxf(lm, __shfl_xor(lm, off, 64));
    if ((t & 63) == 0) red[t >> 6] = lm;
    __syncthreads();
    float m = fmaxf(fmaxf(red[0], red[1]), fmaxf(red[2], red[3]));
    float e0 = __expf(v.x - m), e1 = __expf(v.y - m);
    float e2 = __expf(v.z - m), e3 = __expf(v.w - m);
    float ls = (e0 + e1) + (e2 + e3);
#pragma unroll
    for (int off = 1; off < 64; off <<= 1) ls += __shfl_xor(ls, off, 64);
    __syncthreads();
    if ((t & 63) == 0) red[t >> 6] = ls;
    __syncthreads();
    float inv = 1.f / (((red[0] + red[1]) + (red[2] + red[3])));
    float4 o = {e0 * inv, e1 * inv, e2 * inv, e3 * inv};
    *(float4*)(wp + t * 4) = o;
}

// ---------------- K2b: cf1[b,c,ch] = sum_hw w2[b,c,hw] * x[b,ch,hw] ----------------
__global__ __launch_bounds__(256) void k2b_pool(const float* __restrict__ x,
                                                const float* __restrict__ w2,
                                                float* __restrict__ cf1) {
    __shared__ float pl[NC_ * HW_];     // 20 KB
    int t = threadIdx.x;
    int b = blockIdx.x >> 4, chg = blockIdx.x & 15;
    const float* wb = w2 + (size_t)b * NC_ * HW_;
    for (int i = t; i < NC_ * HW_ / 4; i += 256)
        *(float4*)(pl + i * 4) = *(const float4*)(wb + i * 4);
    __syncthreads();
    int w = t >> 6, lane = t & 63;
    int ch = chg * 4 + w;
    const float* xc = x + ((size_t)b * C_ + ch) * HW_;
    float acc[NC_] = {0.f, 0.f, 0.f, 0.f, 0.f};
#pragma unroll
    for (int i = 0; i < HW_ / 64; i++) {
        int hw = i * 64 + lane;
        float xv = xc[hw];
#pragma unroll
        for (int c = 0; c < NC_; c++) acc[c] += xv * pl[c * HW_ + hw];
    }
#pragma unroll
    for (int c = 0; c < NC_; c++) {
        float a = acc[c];
#pragma unroll
        for (int off = 1; off < 64; off <<= 1) a += __shfl_xor(a, off, 64);
        if (lane == 0) cf1[((size_t)b * NC_ + c) * C_ + ch] = a;
    }
}

// ---------------- K3: MHA1 (n_head=1, dk=96, dv=64) + residual + LN, per batch ----------------
__global__ __launch_bounds__(256) void k3_mha1(const float* __restrict__ cf1,
                                               const float* __restrict__ wq, const float* __restrict__ bq,
                                               const float* __restrict__ mem,
                                               const float* __restrict__ wk, const float* __restrict__ bk,
                                               const float* __restrict__ wv, const float* __restrict__ bv,
                                               const float* __restrict__ fc, const float* __restrict__ fcb,
                                               const float* __restrict__ lng, const float* __restrict__ lnb,
                                               float* __restrict__ cfs) {
    __shared__ float cs[NC_ * C_];
    __shared__ float kh[NC_ * D1_];
    __shared__ float vh[NC_ * DH_];
    __shared__ float q[NC_ * D1_];
    __shared__ float sc[NC_ * NC_];
    __shared__ float pp[NC_ * NC_];
    __shared__ float o[NC_ * C_];
    __shared__ float z[NC_ * C_];
    __shared__ float mu[NC_], rs[NC_];
    int t = threadIdx.x, b = blockIdx.x;
    for (int i = t; i < NC_ * C_; i += 256) cs[i] = cf1[(size_t)b * NC_ * C_ + i];
    for (int idx = t; idx < NC_ * D1_; idx += 256) {
        int i = idx / D1_, k = idx % D1_;
        float a = bk[k];
        for (int d = 0; d < D1_; d++) a += mem[i * D1_ + d] * wk[d * D1_ + k];
        kh[idx] = a;
    }
    for (int idx = t; idx < NC_ * DH_; idx += 256) {
        int i = idx / DH_, dv = idx % DH_;
        float a = bv[dv];
        for (int d = 0; d < D1_; d++) a += mem[i * D1_ + d] * wv[d * DH_ + dv];
        vh[idx] = a;
    }
    __syncthreads();
    for (int idx = t; idx < NC_ * D1_; idx += 256) {
        int i = idx / D1_, k = idx % D1_;
        float a = bq[k];
        for (int c = 0; c < C_; c++) a += cs[i * C_ + c] * wq[c * D1_ + k];
        q[idx] = a;
    }
    __syncthreads();
    if (t < NC_ * NC_) {
        int i = t / NC_, j = t % NC_;
        float a = 0.f;
        for (int k = 0; k < D1_; k++) a += q[i * D1_ + k] * kh[j * D1_ + k];
        sc[t] = a * 0.1020620726159657f;     // 1/sqrt(96)
    }
    __syncthreads();
    if (t < NC_) {
        float m = sc[t * NC_];
        for (int j = 1; j < NC_; j++) m = fmaxf(m, sc[t * NC_ + j]);
        float e[NC_], s = 0.f;
        for (int j = 0; j < NC_; j++) { e[j] = __expf(sc[t * NC_ + j] - m); s += e[j]; }
        float inv = 1.f / s;
        for (int j = 0; j < NC_; j++) pp[t * NC_ + j] = e[j] * inv;
    }
    __syncthreads();
    for (int idx = t; idx < NC_ * C_; idx += 256) {
        int i = idx / C_, dv = idx % C_;
        float a = 0.f;
        for (int j = 0; j < NC_; j++) a += pp[i * NC_ + j] * vh[j * C_ + dv];
        o[idx] = a;
    }
    __syncthreads();
    for (int idx = t; idx < NC_ * C_; idx += 256) {
        int i = idx / C_, dd = idx % C_;
        float a = fcb[dd] + cs[idx];
        for (int c2 = 0; c2 < C_; c2++) a += o[i * C_ + c2] * fc[c2 * C_ + dd];
        z[idx] = a;
    }
    __syncthreads();
    if (t < NC_) {
        float s = 0.f;
        for (int d = 0; d < C_; d++) s += z[t * C_ + d];
        float mm = s / C_;
        float v = 0.f;
        for (int d = 0; d < C_; d++) { float dd2 = z[t * C_ + d] - mm; v += dd2 * dd2; }
        mu[t] = mm; rs[t] = rsqrtf(v / C_ + 1e-6f);
    }
    __syncthreads();
    for (int idx = t; idx < NC_ * C_; idx += 256) {
        int i = idx / C_, dd = idx % C_;
        cfs[(size_t)b * NC_ * C_ + idx] = (z[idx] - mu[i]) * rs[i] * lng[dd] + lnb[dd];
    }
}

// ---------------- K4: cf[b,hw,:] = sum_c weight1[b,hw,c] * cfs[b,c,:] ----------------
__global__ __launch_bounds__(256) void k4_redist(const float* __restrict__ w1,
                                                 const float* __restrict__ cfs,
                                                 float* __restrict__ cf) {
    int e = blockIdx.x * 256 + threadIdx.x;     // < 1048576
    int ch = e & 63, r = (e >> 6) & 1023, b = e >> 16;
    const float* wp = w1 + ((size_t)b * HW_ + r) * NC_;
    const float* cp = cfs + (size_t)b * NC_ * C_;
    float a = 0.f;
#pragma unroll
    for (int c2 = 0; c2 < NC_; c2++) a += wp[c2] * cp[c2 * C_ + ch];
    cf[e] = a;
}

// ---------------- K5: Q/K/V projections -> bf16 [b,h,l,64]; Q pre-scaled by log2e/8 ----------------
__global__ __launch_bounds__(256) void k5_proj(const float* __restrict__ cf,
                                               const float* __restrict__ wq, const float* __restrict__ bq,
                                               const float* __restrict__ wk, const float* __restrict__ bk,
                                               const float* __restrict__ wv, const float* __restrict__ bv,
                                               ushort_t* __restrict__ Qb, ushort_t* __restrict__ Kb,
                                               ushort_t* __restrict__ Vb) {
    __shared__ float rows[8][64];
    int t = threadIdx.x;
    int which = blockIdx.y;
    int m0 = blockIdx.x * 8;
    for (int e = t; e < 8 * 64; e += 256) rows[e >> 6][e & 63] = cf[(size_t)m0 * 64 + e];
    __syncthreads();
    const float* W = (which == 0) ? wq : (which == 1) ? wk : wv;
    const float* bias = (which == 0) ? bq : (which == 1) ? bk : bv;
    ushort_t* dst = (which == 0) ? Qb : (which == 1) ? Kb : Vb;
    // Q scale = (1/sqrt(64)) * log2(e): k6 uses exp2 directly (bare v_exp_f32)
    float scale = (which == 0) ? 0.18033688011112042f : 1.0f;
    int c = t;
    float bb = bias[c];
    float acc[8];
#pragma unroll
    for (int r = 0; r < 8; r++) acc[r] = bb;
    for (int k = 0; k < 64; k++) {
        float wv_ = W[k * 256 + c];
#pragma unroll
        for (int r = 0; r < 8; r++) acc[r] += rows[r][k] * wv_;
    }
    int h = c >> 6, dd = c & 63;
#pragma unroll
    for (int r = 0; r < 8; r++) {
        int m = m0 + r, b = m >> 10, hw = m & 1023;
        dst[(((size_t)(b * NH_ + h) * HW_) + hw) * DH_ + dd] = f2bf(acc[r] * scale);
    }
}

// ---------------- KT: Vt[b,h,d,l] = Vb[b,h,l,d] ----------------
__global__ __launch_bounds__(256) void kt_transpose(const ushort_t* __restrict__ Vb,
                                                    ushort_t* __restrict__ Vt) {
    __shared__ ushort_t tile[64][65];
    int t = threadIdx.x;
    int bh = blockIdx.y;
    int l0 = blockIdx.x * 64;
    const ushort_t* src = Vb + (size_t)bh * HW_ * DH_ + (size_t)l0 * DH_;
    for (int e = t; e < 4096; e += 256) { int l = e >> 6, d = e & 63; tile[d][l] = src[l * 64 + d]; }
    __syncthreads();
    ushort_t* dst = Vt + (size_t)bh * DH_ * HW_ + l0;
    for (int e = t; e < 4096; e += 256) { int d = e >> 6, l = e & 63; dst[(size_t)d * HW_ + l] = tile[d][l]; }
}

// ---------------- K6: MFMA bf16 flash attention v5 — split-K + 2 q-tiles/wave ----------------
// - 2 q-tiles/wave (R5's load amortization: 8 loads serve 18 MFMAs — the R6/R7 1-tile
//   variant doubled per-tile load pressure and was 2x slower).
// - split-K: keys 0..511 / 512..1023 across separate blocks. No-max softmax => partials
//   combine linearly (O=O0+O1, s=s0+s1) in k7. Grid 8qt x 64bh x 2kh = 1024 (4 blocks/CU).
// - XCD swizzle: L%8 == bh%8 (12 MB HBM fetch, measured R6/R7).
// - VALU diet: exp2 (Q pre-scaled by log2e/8), trunc bf16 pack, ones-MFMA denominators.
// - No launch_bounds cap / no manual prefetch (R6 lesson).
__global__ __launch_bounds__(256) void k6_attn(const ushort_t* __restrict__ Qb,
                                               const ushort_t* __restrict__ Kb,
                                               const ushort_t* __restrict__ Vt,
                                               float* __restrict__ aoP0, float* __restrict__ aoP1,
                                               float* __restrict__ sP0, float* __restrict__ sP1) {
    int t = threadIdx.x;
    int w = t >> 6;
    int lane = t & 63;
    int l15 = lane & 15;
    int quad = lane >> 4;
    // decode swizzled block id: L%8 == bh%8
    int L = blockIdx.x;
    int bh_lo = L & 7;
    int r1 = L >> 3;
    int bh_hi = r1 & 7;
    int r2 = r1 >> 3;
    int khalf = r2 & 1;
    int qt = r2 >> 1;                    // 0..7
    int bh = bh_hi * 8 + bh_lo;
    int b = bh >> 2, h = bh & 3;
    const ushort_t* Qp = Qb + (size_t)bh * HW_ * DH_;
    const ushort_t* Kp = Kb + (size_t)bh * HW_ * DH_;
    const ushort_t* Vp = Vt + (size_t)bh * DH_ * HW_;
    int rowA = qt * 128 + w * 16;        // q-tile A
    int rowB = rowA + 64;                // q-tile B
    short8 qa0 = *(const short8*)(Qp + (size_t)(rowA + l15) * DH_ + quad * 8);
    short8 qa1 = *(const short8*)(Qp + (size_t)(rowA + l15) * DH_ + 32 + quad * 8);
    short8 qb0 = *(const short8*)(Qp + (size_t)(rowB + l15) * DH_ + quad * 8);
    short8 qb1 = *(const short8*)(Qp + (size_t)(rowB + l15) * DH_ + 32 + quad * 8);
    // permuted key offsets: S^T tile0 row l15 -> key f0, tile1 -> f0+4
    int f0 = ((l15 >> 2) * 8) + (l15 & 3);
    int kstart = khalf * 512;
    const ushort_t* K0p = Kp + (size_t)(kstart + f0) * DH_ + quad * 8;
    const ushort_t* K1p = Kp + (size_t)(kstart + f0 + 4) * DH_ + quad * 8;
    const ushort_t* Vp0 = Vp + (size_t)(0 * 16 + l15) * HW_ + kstart + quad * 8;
    const ushort_t* Vp1 = Vp + (size_t)(1 * 16 + l15) * HW_ + kstart + quad * 8;
    const ushort_t* Vp2 = Vp + (size_t)(2 * 16 + l15) * HW_ + kstart + quad * 8;
    const ushort_t* Vp3 = Vp + (size_t)(3 * 16 + l15) * HW_ + kstart + quad * 8;
    const short ONE = (short)0x3F80;      // bf16 1.0
    short8 ones = {ONE, ONE, ONE, ONE, ONE, ONE, ONE, ONE};
    f32x4 oA0 = {0,0,0,0}, oA1 = {0,0,0,0}, oA2 = {0,0,0,0}, oA3 = {0,0,0,0};
    f32x4 oB0 = {0,0,0,0}, oB1 = {0,0,0,0}, oB2 = {0,0,0,0}, oB3 = {0,0,0,0};
    f32x4 oSA = {0,0,0,0}, oSB = {0,0,0,0};
#pragma unroll 2
    for (int kt = 0; kt < 16; kt++) {
        int kbase = kt * 32;
        size_t koff = (size_t)kbase * DH_;
        short8 ka0 = *(const short8*)(K0p + koff);
        short8 ka1 = *(const short8*)(K0p + koff + 32);
        short8 kb0 = *(const short8*)(K1p + koff);
        short8 kb1 = *(const short8*)(K1p + koff + 32);
        short8 v0 = *(const short8*)(Vp0 + kbase);
        short8 v1 = *(const short8*)(Vp1 + kbase);
        short8 v2 = *(const short8*)(Vp2 + kbase);
        short8 v3 = *(const short8*)(Vp3 + kbase);
        f32x4 z = {0,0,0,0};
        f32x4 sA0 = MFMA32(ka0, qa0, z);  sA0 = MFMA32(ka1, qa1, sA0);
        f32x4 sA1 = MFMA32(kb0, qa0, z);  sA1 = MFMA32(kb1, qa1, sA1);
        f32x4 sB0 = MFMA32(ka0, qb0, z);  sB0 = MFMA32(ka1, qb1, sB0);
        f32x4 sB1 = MFMA32(kb0, qb0, z);  sB1 = MFMA32(kb1, qb1, sB1);
        // p = exp2(s) (Q pre-scaled by log2e/8; shift-0 softmax is exact, |s| small)
        float a0 = exp2f(sA0[0]), a1 = exp2f(sA0[1]), a2 = exp2f(sA0[2]), a3 = exp2f(sA0[3]);
        float a4 = exp2f(sA1[0]), a5 = exp2f(sA1[1]), a6 = exp2f(sA1[2]), a7 = exp2f(sA1[3]);
        float b0 = exp2f(sB0[0]), b1 = exp2f(sB0[1]), b2 = exp2f(sB0[2]), b3 = exp2f(sB0[3]);
        float b4 = exp2f(sB1[0]), b5 = exp2f(sB1[1]), b6 = exp2f(sB1[2]), b7 = exp2f(sB1[3]);
        union { short8 v; unsigned u[4]; } pfA, pfB;
        pfA.u[0] = pack2_trunc(a0, a1);  pfA.u[1] = pack2_trunc(a2, a3);
        pfA.u[2] = pack2_trunc(a4, a5);  pfA.u[3] = pack2_trunc(a6, a7);
        pfB.u[0] = pack2_trunc(b0, b1);  pfB.u[1] = pack2_trunc(b2, b3);
        pfB.u[2] = pack2_trunc(b4, b5);  pfB.u[3] = pack2_trunc(b6, b7);
        oA0 = MFMA32(v0, pfA.v, oA0);
        oA1 = MFMA32(v1, pfA.v, oA1);
        oA2 = MFMA32(v2, pfA.v, oA2);
        oA3 = MFMA32(v3, pfA.v, oA3);
        oSA = MFMA32(ones, pfA.v, oSA);
        oB0 = MFMA32(v0, pfB.v, oB0);
        oB1 = MFMA32(v1, pfB.v, oB1);
        oB2 = MFMA32(v2, pfB.v, oB2);
        oB3 = MFMA32(v3, pfB.v, oB3);
        oSB = MFMA32(ones, pfB.v, oSB);
    }
    float* aoP = khalf ? aoP1 : aoP0;
    float* sP  = khalf ? sP1  : sP0;
    {   // q-tile A, unnormalized
        int rowg = rowA + l15;
        float* aop = aoP + ((size_t)(b * HW_ + rowg)) * (NH_ * DH_) + h * DH_ + quad * 4;
        *(float4*)(aop + 0)  = *(float4*)&oA0;
        *(float4*)(aop + 16) = *(float4*)&oA1;
        *(float4*)(aop + 32) = *(float4*)&oA2;
        *(float4*)(aop + 48) = *(float4*)&oA3;
    }
    {   // q-tile B
        int rowg = rowB + l15;
        float* aop = aoP + ((size_t)(b * HW_ + rowg)) * (NH_ * DH_) + h * DH_ + quad * 4;
        *(float4*)(aop + 0)  = *(float4*)&oB0;
        *(float4*)(aop + 16) = *(float4*)&oB1;
        *(float4*)(aop + 32) = *(float4*)&oB2;
        *(float4*)(aop + 48) = *(float4*)&oB3;
    }
    if (quad == 0) {   // partial denominators (all oS regs equal per column)
        sP[(size_t)(b * HW_ + rowA + l15) * NH_ + h] = oSA[0];
        sP[(size_t)(b * HW_ + rowB + l15) * NH_ + h] = oSB[0];
    }
}

// ---------------- K7: combine attention partials + fc + residual + LN -> [b,64,32,32] ----------------
__global__ __launch_bounds__(256) void k7_final(const float* __restrict__ aoP0,
                                                const float* __restrict__ aoP1,
                                                const float* __restrict__ sP0,
                                                const float* __restrict__ sP1,
                                                const float* __restrict__ fc, const float* __restrict__ fcb,
                                                const float* __restrict__ cf,
                                                const float* __restrict__ lng, const float* __restrict__ lnb,
                                                float* __restrict__ out) {
    __shared__ float srow[16 * 256];      // 16 KB
    __shared__ float rinv[64];            // per (row, head) 1/(s0+s1)
    __shared__ float T[64 * 17];          // padded transpose buffer
    int t = threadIdx.x, w = t >> 6, d = t & 63;
    int m0 = blockIdx.x * 16;
    if (t < 64) {
        int row = t >> 2, hh = t & 3;
        float s = sP0[(size_t)(m0 + row) * NH_ + hh] + sP1[(size_t)(m0 + row) * NH_ + hh];
        rinv[t] = 1.f / s;
    }
    __syncthreads();
    for (int i = t; i < 1024; i += 256) {
        float4 a = *(const float4*)&aoP0[(size_t)m0 * 256 + i * 4];
        float4 b4 = *(const float4*)&aoP1[(size_t)m0 * 256 + i * 4];
        int e = i * 4;
        int row = e >> 8, hh = (e >> 6) & 3;
        float r = rinv[row * 4 + hh];
        float4 o = {(a.x + b4.x) * r, (a.y + b4.y) * r, (a.z + b4.z) * r, (a.w + b4.w) * r};
        *(float4*)&srow[e] = o;
    }
    __syncthreads();
    float bias = fcb[d];
    float a[4];
#pragma unroll
    for (int j = 0; j < 4; j++)
        a[j] = bias + cf[(size_t)(m0 + w * 4 + j) * 64 + d];
    for (int k = 0; k < 256; k++) {
        float f = fc[k * 64 + d];
#pragma unroll
        for (int j = 0; j < 4; j++) a[j] += srow[(w * 4 + j) * 256 + k] * f;
    }
    float g = lng[d], be = lnb[d];
#pragma unroll
    for (int j = 0; j < 4; j++) {
        float s1 = a[j], s2 = a[j] * a[j];
#pragma unroll
        for (int off = 1; off < 64; off <<= 1) {
            s1 += __shfl_xor(s1, off, 64);
            s2 += __shfl_xor(s2, off, 64);
        }
        float mu = s1 * (1.f / 64.f);
        float var = s2 * (1.f / 64.f) - mu * mu;
        float rstd = rsqrtf(var + 1e-6f);
        T[d * 17 + w * 4 + j] = (a[j] - mu) * rstd * g + be;
    }
    __syncthreads();
    int ch = t >> 2, part = t & 3;
    int b = m0 >> 10, hw0 = m0 & 1023;
    float4 v = {T[ch * 17 + part * 4 + 0], T[ch * 17 + part * 4 + 1],
                T[ch * 17 + part * 4 + 2], T[ch * 17 + part * 4 + 3]};
    *(float4*)&out[((size_t)b * 64 + ch) * 1024 + hw0 + part * 4] = v;
}

// ---------------- launcher ----------------
extern "C" void kernel_launch(void* const* d_in, const int* in_sizes, int n_in,
                              void* d_out, int out_size, void* d_ws, size_t ws_size,
                              hipStream_t stream) {
    const float* x      = (const float*)d_in[0];
    const float* memory = (const float*)d_in[1];
    const float* wb_w   = (const float*)d_in[2];
    const float* wb_b   = (const float*)d_in[3];
    const float* a1_wq  = (const float*)d_in[4];
    const float* a1_bq  = (const float*)d_in[5];
    const float* a1_wk  = (const float*)d_in[6];
    const float* a1_bk  = (const float*)d_in[7];
    const float* a1_wv  = (const float*)d_in[8];
    const float* a1_bv  = (const float*)d_in[9];
    const float* a1_fc  = (const float*)d_in[10];
    const float* a1_fcb = (const float*)d_in[11];
    const float* a1_ln_g = (const float*)d_in[12];
    const float* a1_ln_b = (const float*)d_in[13];
    const float* a2_wq  = (const float*)d_in[14];
    const float* a2_bq  = (const float*)d_in[15];
    const float* a2_wk  = (const float*)d_in[16];
    const float* a2_bk  = (const float*)d_in[17];
    const float* a2_wv  = (const float*)d_in[18];
    const float* a2_bv  = (const float*)d_in[19];
    const float* a2_fc  = (const float*)d_in[20];
    const float* a2_fcb = (const float*)d_in[21];
    const float* a2_ln_g = (const float*)d_in[22];
    const float* a2_ln_b = (const float*)d_in[23];

    float* ws = (float*)d_ws;
    float* logitsT = ws;                                   // 81920
    float* w2buf = logitsT + 81920;                        // 81920
    float* w1  = w2buf + 81920;                            // 81920
    float* cf1 = w1 + 81920;                               // 5120
    float* cfs = cf1 + 5120;                               // 5120
    float* cf  = cfs + 5120;                               // 1048576
    float* aoP0 = cf + 1048576;                            // 4194304
    float* aoP1 = aoP0 + 4194304;                          // 4194304
    float* sP0  = aoP1 + 4194304;                          // 65536
    float* sP1  = sP0 + 65536;                             // 65536
    ushort_t* Qb = (ushort_t*)(sP1 + 65536);               // 4.19M ushorts each
    ushort_t* Kb = Qb + 16 * 4 * 1024 * 64;
    ushort_t* Vb = Kb + 16 * 4 * 1024 * 64;
    ushort_t* Vt = Vb + 16 * 4 * 1024 * 64;

    k1_logits<<<256, 64, 0, stream>>>(x, wb_w, wb_b, logitsT, w1);
    k2a_softmax<<<80, 256, 0, stream>>>(logitsT, w2buf);
    k2b_pool<<<256, 256, 0, stream>>>(x, w2buf, cf1);
    k3_mha1<<<16, 256, 0, stream>>>(cf1, a1_wq, a1_bq, memory, a1_wk, a1_bk,
                                    a1_wv, a1_bv, a1_fc, a1_fcb,
                                    a1_ln_g, a1_ln_b, cfs);
    k4_redist<<<4096, 256, 0, stream>>>(w1, cfs, cf);
    k5_proj<<<dim3(2048, 3), 256, 0, stream>>>(cf, a2_wq, a2_bq, a2_wk, a2_bk,
                                               a2_wv, a2_bv, Qb, Kb, Vb);
    kt_transpose<<<dim3(16, 64), 256, 0, stream>>>(Vb, Vt);
    k6_attn<<<1024, 256, 0, stream>>>(Qb, Kb, Vt, aoP0, aoP1, sP0, sP1);
    k7_final<<<1024, 256, 0, stream>>>(aoP0, aoP1, sP0, sP1, a2_fc, a2_fcb, cf,
                                       a2_ln_g, a2_ln_b, (float*)d_out);
}

// Round 9
// 247.029 us; speedup vs baseline: 1.2380x; 1.0540x over previous
//
#include <hip/hip_runtime.h>
#include <math.h>

typedef unsigned short ushort_t;
typedef __attribute__((ext_vector_type(8))) short short8;
typedef __attribute__((ext_vector_type(4))) float f32x4;

#define B_  16
#define HW_ 1024
#define C_  64
#define NC_ 5
#define D1_ 96
#define NH_ 4
#define DH_ 64

#define MFMA32(A,B,C) __builtin_amdgcn_mfma_f32_16x16x32_bf16(A,B,C,0,0,0)

__device__ __forceinline__ ushort_t f2bf(float f) {
    unsigned u = __float_as_uint(f);
    u = u + 0x7fffu + ((u >> 16) & 1u);   // round-to-nearest-even
    return (ushort_t)(u >> 16);
}

// truncating bf16 pair-pack: one op per 2 elements (lo -> low short, hi -> high short)
__device__ __forceinline__ unsigned pack2_trunc(float lo, float hi) {
    return (__float_as_uint(hi) & 0xffff0000u) | (__float_as_uint(lo) >> 16);
}
__device__ __forceinline__ float bf_lo(unsigned u) { return __uint_as_float(u << 16); }
__device__ __forceinline__ float bf_hi(unsigned u) { return __uint_as_float(u & 0xffff0000u); }

// ---------------- K1: logits = xt @ wb_w + wb_b ; weight1 = softmax over classes ----------------
__global__ __launch_bounds__(64) void k1_logits(const float* __restrict__ x,
                                                const float* __restrict__ wb_w,
                                                const float* __restrict__ wb_b,
                                                float* __restrict__ logitsT,
                                                float* __restrict__ w1) {
    int b = blockIdx.x >> 4;
    int hw = (blockIdx.x & 15) * 64 + threadIdx.x;
    const float* xb = x + (size_t)b * C_ * HW_;
    float acc[NC_];
#pragma unroll
    for (int j = 0; j < NC_; j++) acc[j] = wb_b[j];
#pragma unroll 8
    for (int c = 0; c < C_; c++) {
        float xv = xb[c * HW_ + hw];
#pragma unroll
        for (int j = 0; j < NC_; j++) acc[j] += xv * wb_w[c * NC_ + j];
    }
    float m = acc[0];
#pragma unroll
    for (int j = 1; j < NC_; j++) m = fmaxf(m, acc[j]);
    float e[NC_], s = 0.f;
#pragma unroll
    for (int j = 0; j < NC_; j++) { e[j] = __expf(acc[j] - m); s += e[j]; }
    float inv = 1.f / s;
    int idx = b * HW_ + hw;
#pragma unroll
    for (int j = 0; j < NC_; j++) {
        logitsT[((size_t)b * NC_ + j) * HW_ + hw] = acc[j];
        w1[(size_t)idx * NC_ + j] = e[j] * inv;
    }
}

// ---------------- K2: fused softmax-over-HW + pooling: cf1[b,c,ch] ----------------
// block (b, chg): stage logits[b][5][1024] in LDS, softmax in-block (wave per row),
// then wave-per-channel pooling with coalesced x reads.
__global__ __launch_bounds__(256) void k2b_pool(const float* __restrict__ x,
                                                const float* __restrict__ logitsT,
                                                float* __restrict__ cf1) {
    __shared__ float pl[NC_ * HW_];     // 20 KB
    __shared__ float sinv[NC_];
    int t = threadIdx.x;
    int b = blockIdx.x >> 4, chg = blockIdx.x & 15;
    const float* lp = logitsT + (size_t)b * NC_ * HW_;
    for (int i = t * 4; i < NC_ * HW_; i += 1024)
        *(float4*)(pl + i) = *(const float4*)(lp + i);
    __syncthreads();
    int w = t >> 6, lane = t & 63;
    for (int r = w; r < NC_; r += 4) {
        float m = -1e30f;
        for (int i = lane; i < HW_; i += 64) m = fmaxf(m, pl[r * HW_ + i]);
#pragma unroll
        for (int off = 1; off < 64; off <<= 1) m = fmaxf(m, __shfl_xor(m, off, 64));
        float s = 0.f;
        for (int i = lane; i < HW_; i += 64) {
            float e = __expf(pl[r * HW_ + i] - m);
            pl[r * HW_ + i] = e;
            s += e;
        }
#pragma unroll
        for (int off = 1; off < 64; off <<= 1) s += __shfl_xor(s, off, 64);
        if (lane == 0) sinv[r] = 1.f / s;
    }
    __syncthreads();
    int ch = chg * 4 + w;
    const float* xc = x + ((size_t)b * C_ + ch) * HW_;
    float acc[NC_] = {0.f, 0.f, 0.f, 0.f, 0.f};
#pragma unroll
    for (int i = 0; i < HW_ / 64; i++) {
        int hw = i * 64 + lane;
        float xv = xc[hw];
#pragma unroll
        for (int c = 0; c < NC_; c++) acc[c] += xv * pl[c * HW_ + hw];
    }
#pragma unroll
    for (int c = 0; c < NC_; c++) {
        float a = acc[c];
#pragma unroll
        for (int off = 1; off < 64; off <<= 1) a += __shfl_xor(a, off, 64);
        if (lane == 0) cf1[((size_t)b * NC_ + c) * C_ + ch] = a * sinv[c];
    }
}

// ---------------- K3: MHA1 (n_head=1, dk=96, dv=64) + residual + LN, per batch ----------------
__global__ __launch_bounds__(256) void k3_mha1(const float* __restrict__ cf1,
                                               const float* __restrict__ wq, const float* __restrict__ bq,
                                               const float* __restrict__ mem,
                                               const float* __restrict__ wk, const float* __restrict__ bk,
                                               const float* __restrict__ wv, const float* __restrict__ bv,
                                               const float* __restrict__ fc, const float* __restrict__ fcb,
                                               const float* __restrict__ lng, const float* __restrict__ lnb,
                                               float* __restrict__ cfs) {
    __shared__ float cs[NC_ * C_];
    __shared__ float kh[NC_ * D1_];
    __shared__ float vh[NC_ * DH_];
    __shared__ float q[NC_ * D1_];
    __shared__ float sc[NC_ * NC_];
    __shared__ float pp[NC_ * NC_];
    __shared__ float o[NC_ * C_];
    __shared__ float z[NC_ * C_];
    __shared__ float mu[NC_], rs[NC_];
    int t = threadIdx.x, b = blockIdx.x;
    for (int i = t; i < NC_ * C_; i += 256) cs[i] = cf1[(size_t)b * NC_ * C_ + i];
    for (int idx = t; idx < NC_ * D1_; idx += 256) {
        int i = idx / D1_, k = idx % D1_;
        float a = bk[k];
        for (int d = 0; d < D1_; d++) a += mem[i * D1_ + d] * wk[d * D1_ + k];
        kh[idx] = a;
    }
    for (int idx = t; idx < NC_ * DH_; idx += 256) {
        int i = idx / DH_, dv = idx % DH_;
        float a = bv[dv];
        for (int d = 0; d < D1_; d++) a += mem[i * D1_ + d] * wv[d * DH_ + dv];
        vh[idx] = a;
    }
    __syncthreads();
    for (int idx = t; idx < NC_ * D1_; idx += 256) {
        int i = idx / D1_, k = idx % D1_;
        float a = bq[k];
        for (int c = 0; c < C_; c++) a += cs[i * C_ + c] * wq[c * D1_ + k];
        q[idx] = a;
    }
    __syncthreads();
    if (t < NC_ * NC_) {
        int i = t / NC_, j = t % NC_;
        float a = 0.f;
        for (int k = 0; k < D1_; k++) a += q[i * D1_ + k] * kh[j * D1_ + k];
        sc[t] = a * 0.1020620726159657f;     // 1/sqrt(96)
    }
    __syncthreads();
    if (t < NC_) {
        float m = sc[t * NC_];
        for (int j = 1; j < NC_; j++) m = fmaxf(m, sc[t * NC_ + j]);
        float e[NC_], s = 0.f;
        for (int j = 0; j < NC_; j++) { e[j] = __expf(sc[t * NC_ + j] - m); s += e[j]; }
        float inv = 1.f / s;
        for (int j = 0; j < NC_; j++) pp[t * NC_ + j] = e[j] * inv;
    }
    __syncthreads();
    for (int idx = t; idx < NC_ * C_; idx += 256) {
        int i = idx / C_, dv = idx % C_;
        float a = 0.f;
        for (int j = 0; j < NC_; j++) a += pp[i * NC_ + j] * vh[j * C_ + dv];
        o[idx] = a;
    }
    __syncthreads();
    for (int idx = t; idx < NC_ * C_; idx += 256) {
        int i = idx / C_, dd = idx % C_;
        float a = fcb[dd] + cs[idx];
        for (int c2 = 0; c2 < C_; c2++) a += o[i * C_ + c2] * fc[c2 * C_ + dd];
        z[idx] = a;
    }
    __syncthreads();
    if (t < NC_) {
        float s = 0.f;
        for (int d = 0; d < C_; d++) s += z[t * C_ + d];
        float mm = s / C_;
        float v = 0.f;
        for (int d = 0; d < C_; d++) { float dd2 = z[t * C_ + d] - mm; v += dd2 * dd2; }
        mu[t] = mm; rs[t] = rsqrtf(v / C_ + 1e-6f);
    }
    __syncthreads();
    for (int idx = t; idx < NC_ * C_; idx += 256) {
        int i = idx / C_, dd = idx % C_;
        cfs[(size_t)b * NC_ * C_ + idx] = (z[idx] - mu[i]) * rs[i] * lng[dd] + lnb[dd];
    }
}

// ---------------- K5: inline redistribution (w1·cfs) + Q/K/V projections ----------------
// Q/K -> bf16 [b,h,l,64] (Q pre-scaled by log2e/8); V -> Vt [b,h,dv,l] DIRECTLY
// (each thread owns 8 consecutive l for one (h,dv): one 16B store = fused transpose).
__global__ __launch_bounds__(256) void k5_proj(const float* __restrict__ w1,
                                               const float* __restrict__ cfs,
                                               const float* __restrict__ wq, const float* __restrict__ bq,
                                               const float* __restrict__ wk, const float* __restrict__ bk,
                                               const float* __restrict__ wv, const float* __restrict__ bv,
                                               ushort_t* __restrict__ Qb, ushort_t* __restrict__ Kb,
                                               ushort_t* __restrict__ Vt) {
    __shared__ float rows[8][64];
    int t = threadIdx.x;
    int which = blockIdx.y;
    int m0 = blockIdx.x * 8;
    int b5 = m0 >> 10;
    // recompute cf rows from w1 (L1-broadcast) and cfs (L2-hot): 5 FMA/element
    {
        int ch = t & 63, rr = t >> 6;
        const float* cp = cfs + (size_t)b5 * NC_ * C_;
        for (int r = rr; r < 8; r += 4) {
            const float* w1p = w1 + (size_t)(m0 + r) * NC_;
            float a = 0.f;
#pragma unroll
            for (int c = 0; c < NC_; c++) a += w1p[c] * cp[c * 64 + ch];
            rows[r][ch] = a;
        }
    }
    __syncthreads();
    const float* W = (which == 0) ? wq : (which == 1) ? wk : wv;
    const float* bias = (which == 0) ? bq : (which == 1) ? bk : bv;
    // Q scale = (1/sqrt(64)) * log2(e): k6 uses exp2 directly
    float scale = (which == 0) ? 0.18033688011112042f : 1.0f;
    int c = t;
    float bb = bias[c];
    float acc[8];
#pragma unroll
    for (int r = 0; r < 8; r++) acc[r] = bb;
    for (int k = 0; k < 64; k++) {
        float wv_ = W[k * 256 + c];
#pragma unroll
        for (int r = 0; r < 8; r++) acc[r] += rows[r][k] * wv_;
    }
    int h = c >> 6, dd = c & 63;
    if (which == 2) {
        // Vt[b,h,dv,l]: 8 consecutive l -> one 16B store
        union { ushort_t s[8]; uint4 u; } pk;
#pragma unroll
        for (int r = 0; r < 8; r++) pk.s[r] = f2bf(acc[r]);
        int l0 = m0 & 1023;
        *(uint4*)(Vt + ((size_t)(b5 * NH_ + h) * DH_ + dd) * HW_ + l0) = pk.u;
    } else {
        ushort_t* dst = (which == 0) ? Qb : Kb;
#pragma unroll
        for (int r = 0; r < 8; r++) {
            int m = m0 + r, b = m >> 10, hw = m & 1023;
            dst[(((size_t)(b * NH_ + h) * HW_) + hw) * DH_ + dd] = f2bf(acc[r] * scale);
        }
    }
}

// ---------------- K6: MFMA bf16 flash attention — split-K + 2 q-tiles/wave ----------------
// (R8 structure, proven.) ao partials now bf16 (halved write traffic).
__global__ __launch_bounds__(256) void k6_attn(const ushort_t* __restrict__ Qb,
                                               const ushort_t* __restrict__ Kb,
                                               const ushort_t* __restrict__ Vt,
                                               ushort_t* __restrict__ aoP0, ushort_t* __restrict__ aoP1,
                                               float* __restrict__ sP0, float* __restrict__ sP1) {
    int t = threadIdx.x;
    int w = t >> 6;
    int lane = t & 63;
    int l15 = lane & 15;
    int quad = lane >> 4;
    // decode swizzled block id: L%8 == bh%8 (XCD locality for K/V)
    int L = blockIdx.x;
    int bh_lo = L & 7;
    int r1 = L >> 3;
    int bh_hi = r1 & 7;
    int r2 = r1 >> 3;
    int khalf = r2 & 1;
    int qt = r2 >> 1;                    // 0..7
    int bh = bh_hi * 8 + bh_lo;
    int b = bh >> 2, h = bh & 3;
    const ushort_t* Qp = Qb + (size_t)bh * HW_ * DH_;
    const ushort_t* Kp = Kb + (size_t)bh * HW_ * DH_;
    const ushort_t* Vp = Vt + (size_t)bh * DH_ * HW_;
    int rowA = qt * 128 + w * 16;        // q-tile A
    int rowB = rowA + 64;                // q-tile B
    short8 qa0 = *(const short8*)(Qp + (size_t)(rowA + l15) * DH_ + quad * 8);
    short8 qa1 = *(const short8*)(Qp + (size_t)(rowA + l15) * DH_ + 32 + quad * 8);
    short8 qb0 = *(const short8*)(Qp + (size_t)(rowB + l15) * DH_ + quad * 8);
    short8 qb1 = *(const short8*)(Qp + (size_t)(rowB + l15) * DH_ + 32 + quad * 8);
    // permuted key offsets: S^T tile0 row l15 -> key f0, tile1 -> f0+4
    int f0 = ((l15 >> 2) * 8) + (l15 & 3);
    int kstart = khalf * 512;
    const ushort_t* K0p = Kp + (size_t)(kstart + f0) * DH_ + quad * 8;
    const ushort_t* K1p = Kp + (size_t)(kstart + f0 + 4) * DH_ + quad * 8;
    const ushort_t* Vp0 = Vp + (size_t)(0 * 16 + l15) * HW_ + kstart + quad * 8;
    const ushort_t* Vp1 = Vp + (size_t)(1 * 16 + l15) * HW_ + kstart + quad * 8;
    const ushort_t* Vp2 = Vp + (size_t)(2 * 16 + l15) * HW_ + kstart + quad * 8;
    const ushort_t* Vp3 = Vp + (size_t)(3 * 16 + l15) * HW_ + kstart + quad * 8;
    const short ONE = (short)0x3F80;      // bf16 1.0
    short8 ones = {ONE, ONE, ONE, ONE, ONE, ONE, ONE, ONE};
    f32x4 oA0 = {0,0,0,0}, oA1 = {0,0,0,0}, oA2 = {0,0,0,0}, oA3 = {0,0,0,0};
    f32x4 oB0 = {0,0,0,0}, oB1 = {0,0,0,0}, oB2 = {0,0,0,0}, oB3 = {0,0,0,0};
    f32x4 oSA = {0,0,0,0}, oSB = {0,0,0,0};
#pragma unroll 2
    for (int kt = 0; kt < 16; kt++) {
        int kbase = kt * 32;
        size_t koff = (size_t)kbase * DH_;
        short8 ka0 = *(const short8*)(K0p + koff);
        short8 ka1 = *(const short8*)(K0p + koff + 32);
        short8 kb0 = *(const short8*)(K1p + koff);
        short8 kb1 = *(const short8*)(K1p + koff + 32);
        short8 v0 = *(const short8*)(Vp0 + kbase);
        short8 v1 = *(const short8*)(Vp1 + kbase);
        short8 v2 = *(const short8*)(Vp2 + kbase);
        short8 v3 = *(const short8*)(Vp3 + kbase);
        f32x4 z = {0,0,0,0};
        f32x4 sA0 = MFMA32(ka0, qa0, z);  sA0 = MFMA32(ka1, qa1, sA0);
        f32x4 sA1 = MFMA32(kb0, qa0, z);  sA1 = MFMA32(kb1, qa1, sA1);
        f32x4 sB0 = MFMA32(ka0, qb0, z);  sB0 = MFMA32(ka1, qb1, sB0);
        f32x4 sB1 = MFMA32(kb0, qb0, z);  sB1 = MFMA32(kb1, qb1, sB1);
        float a0 = exp2f(sA0[0]), a1 = exp2f(sA0[1]), a2 = exp2f(sA0[2]), a3 = exp2f(sA0[3]);
        float a4 = exp2f(sA1[0]), a5 = exp2f(sA1[1]), a6 = exp2f(sA1[2]), a7 = exp2f(sA1[3]);
        float b0 = exp2f(sB0[0]), b1 = exp2f(sB0[1]), b2 = exp2f(sB0[2]), b3 = exp2f(sB0[3]);
        float b4 = exp2f(sB1[0]), b5 = exp2f(sB1[1]), b6 = exp2f(sB1[2]), b7 = exp2f(sB1[3]);
        union { short8 v; unsigned u[4]; } pfA, pfB;
        pfA.u[0] = pack2_trunc(a0, a1);  pfA.u[1] = pack2_trunc(a2, a3);
        pfA.u[2] = pack2_trunc(a4, a5);  pfA.u[3] = pack2_trunc(a6, a7);
        pfB.u[0] = pack2_trunc(b0, b1);  pfB.u[1] = pack2_trunc(b2, b3);
        pfB.u[2] = pack2_trunc(b4, b5);  pfB.u[3] = pack2_trunc(b6, b7);
        oA0 = MFMA32(v0, pfA.v, oA0);
        oA1 = MFMA32(v1, pfA.v, oA1);
        oA2 = MFMA32(v2, pfA.v, oA2);
        oA3 = MFMA32(v3, pfA.v, oA3);
        oSA = MFMA32(ones, pfA.v, oSA);
        oB0 = MFMA32(v0, pfB.v, oB0);
        oB1 = MFMA32(v1, pfB.v, oB1);
        oB2 = MFMA32(v2, pfB.v, oB2);
        oB3 = MFMA32(v3, pfB.v, oB3);
        oSB = MFMA32(ones, pfB.v, oSB);
    }
    ushort_t* aoP = khalf ? aoP1 : aoP0;
    float* sP = khalf ? sP1 : sP0;
    {   // q-tile A, unnormalized bf16 partials
        ushort_t* aop = aoP + ((size_t)(b * HW_ + rowA + l15)) * 256 + h * 64 + quad * 4;
        uint2 u;
        u.x = pack2_trunc(oA0[0], oA0[1]); u.y = pack2_trunc(oA0[2], oA0[3]);
        *(uint2*)(aop + 0) = u;
        u.x = pack2_trunc(oA1[0], oA1[1]); u.y = pack2_trunc(oA1[2], oA1[3]);
        *(uint2*)(aop + 16) = u;
        u.x = pack2_trunc(oA2[0], oA2[1]); u.y = pack2_trunc(oA2[2], oA2[3]);
        *(uint2*)(aop + 32) = u;
        u.x = pack2_trunc(oA3[0], oA3[1]); u.y = pack2_trunc(oA3[2], oA3[3]);
        *(uint2*)(aop + 48) = u;
    }
    {   // q-tile B
        ushort_t* aop = aoP + ((size_t)(b * HW_ + rowB + l15)) * 256 + h * 64 + quad * 4;
        uint2 u;
        u.x = pack2_trunc(oB0[0], oB0[1]); u.y = pack2_trunc(oB0[2], oB0[3]);
        *(uint2*)(aop + 0) = u;
        u.x = pack2_trunc(oB1[0], oB1[1]); u.y = pack2_trunc(oB1[2], oB1[3]);
        *(uint2*)(aop + 16) = u;
        u.x = pack2_trunc(oB2[0], oB2[1]); u.y = pack2_trunc(oB2[2], oB2[3]);
        *(uint2*)(aop + 32) = u;
        u.x = pack2_trunc(oB3[0], oB3[1]); u.y = pack2_trunc(oB3[2], oB3[3]);
        *(uint2*)(aop + 48) = u;
    }
    if (quad == 0) {   // partial denominators (f32)
        sP[(size_t)(b * HW_ + rowA + l15) * NH_ + h] = oSA[0];
        sP[(size_t)(b * HW_ + rowB + l15) * NH_ + h] = oSB[0];
    }
}

// ---------------- K7: combine bf16 partials + inline residual (w1·cfs) + fc + LN ----------------
__global__ __launch_bounds__(256) void k7_final(const ushort_t* __restrict__ aoP0,
                                                const ushort_t* __restrict__ aoP1,
                                                const float* __restrict__ sP0,
                                                const float* __restrict__ sP1,
                                                const float* __restrict__ w1,
                                                const float* __restrict__ cfs,
                                                const float* __restrict__ fc, const float* __restrict__ fcb,
                                                const float* __restrict__ lng, const float* __restrict__ lnb,
                                                float* __restrict__ out) {
    __shared__ float srow[16 * 256];      // 16 KB
    __shared__ float rinv[64];            // per (row, head) 1/(s0+s1)
    __shared__ float T[64 * 17];          // padded transpose buffer
    int t = threadIdx.x, w = t >> 6, d = t & 63;
    int m0 = blockIdx.x * 16;
    int b = m0 >> 10;
    if (t < 64) {
        int row = t >> 2, hh = t & 3;
        float s = sP0[(size_t)(m0 + row) * NH_ + hh] + sP1[(size_t)(m0 + row) * NH_ + hh];
        rinv[t] = 1.f / s;
    }
    __syncthreads();
    for (int i = t; i < 512; i += 256) {          // 512 chunks of 8 bf16 elements
        uint4 a  = *(const uint4*)(aoP0 + (size_t)m0 * 256 + i * 8);
        uint4 c4 = *(const uint4*)(aoP1 + (size_t)m0 * 256 + i * 8);
        int e = i * 8, row = e >> 8, hh = (e >> 6) & 3;
        float r = rinv[row * 4 + hh];
        srow[e + 0] = (bf_lo(a.x) + bf_lo(c4.x)) * r;
        srow[e + 1] = (bf_hi(a.x) + bf_hi(c4.x)) * r;
        srow[e + 2] = (bf_lo(a.y) + bf_lo(c4.y)) * r;
        srow[e + 3] = (bf_hi(a.y) + bf_hi(c4.y)) * r;
        srow[e + 4] = (bf_lo(a.z) + bf_lo(c4.z)) * r;
        srow[e + 5] = (bf_hi(a.z) + bf_hi(c4.z)) * r;
        srow[e + 6] = (bf_lo(a.w) + bf_lo(c4.w)) * r;
        srow[e + 7] = (bf_hi(a.w) + bf_hi(c4.w)) * r;
    }
    __syncthreads();
    float bias = fcb[d];
    const float* cp = cfs + (size_t)b * NC_ * C_;
    float a[4];
#pragma unroll
    for (int j = 0; j < 4; j++) {
        int m = m0 + w * 4 + j;
        const float* w1p = w1 + (size_t)m * NC_;
        float acc = bias;
#pragma unroll
        for (int c = 0; c < NC_; c++) acc += w1p[c] * cp[c * 64 + d];   // inline redistribution
        a[j] = acc;
    }
    for (int k = 0; k < 256; k++) {
        float f = fc[k * 64 + d];
#pragma unroll
        for (int j = 0; j < 4; j++) a[j] += srow[(w * 4 + j) * 256 + k] * f;
    }
    float g = lng[d], be = lnb[d];
#pragma unroll
    for (int j = 0; j < 4; j++) {
        float s1 = a[j], s2 = a[j] * a[j];
#pragma unroll
        for (int off = 1; off < 64; off <<= 1) {
            s1 += __shfl_xor(s1, off, 64);
            s2 += __shfl_xor(s2, off, 64);
        }
        float mu = s1 * (1.f / 64.f);
        float var = s2 * (1.f / 64.f) - mu * mu;
        float rstd = rsqrtf(var + 1e-6f);
        T[d * 17 + w * 4 + j] = (a[j] - mu) * rstd * g + be;
    }
    __syncthreads();
    int ch = t >> 2, part = t & 3;
    int hw0 = m0 & 1023;
    float4 v = {T[ch * 17 + part * 4 + 0], T[ch * 17 + part * 4 + 1],
                T[ch * 17 + part * 4 + 2], T[ch * 17 + part * 4 + 3]};
    *(float4*)&out[((size_t)b * 64 + ch) * 1024 + hw0 + part * 4] = v;
}

// ---------------- launcher: 6 dispatches (was 9) ----------------
extern "C" void kernel_launch(void* const* d_in, const int* in_sizes, int n_in,
                              void* d_out, int out_size, void* d_ws, size_t ws_size,
                              hipStream_t stream) {
    const float* x      = (const float*)d_in[0];
    const float* memory = (const float*)d_in[1];
    const float* wb_w   = (const float*)d_in[2];
    const float* wb_b   = (const float*)d_in[3];
    const float* a1_wq  = (const float*)d_in[4];
    const float* a1_bq  = (const float*)d_in[5];
    const float* a1_wk  = (const float*)d_in[6];
    const float* a1_bk  = (const float*)d_in[7];
    const float* a1_wv  = (const float*)d_in[8];
    const float* a1_bv  = (const float*)d_in[9];
    const float* a1_fc  = (const float*)d_in[10];
    const float* a1_fcb = (const float*)d_in[11];
    const float* a1_ln_g = (const float*)d_in[12];
    const float* a1_ln_b = (const float*)d_in[13];
    const float* a2_wq  = (const float*)d_in[14];
    const float* a2_bq  = (const float*)d_in[15];
    const float* a2_wk  = (const float*)d_in[16];
    const float* a2_bk  = (const float*)d_in[17];
    const float* a2_wv  = (const float*)d_in[18];
    const float* a2_bv  = (const float*)d_in[19];
    const float* a2_fc  = (const float*)d_in[20];
    const float* a2_fcb = (const float*)d_in[21];
    const float* a2_ln_g = (const float*)d_in[22];
    const float* a2_ln_b = (const float*)d_in[23];

    float* ws = (float*)d_ws;
    float* logitsT = ws;                                   // 81920 f
    float* w1  = logitsT + 81920;                          // 81920 f
    float* cf1 = w1 + 81920;                               // 5120 f
    float* cfs = cf1 + 5120;                               // 5120 f
    float* sP0 = cfs + 5120;                               // 65536 f
    float* sP1 = sP0 + 65536;                              // 65536 f
    ushort_t* aoP0 = (ushort_t*)(sP1 + 65536);             // 4,194,304 ushorts each
    ushort_t* aoP1 = aoP0 + 4194304;
    ushort_t* Qb = aoP1 + 4194304;
    ushort_t* Kb = Qb + 4194304;
    ushort_t* Vt = Kb + 4194304;                           // total ~43 MB

    k1_logits<<<256, 64, 0, stream>>>(x, wb_w, wb_b, logitsT, w1);
    k2b_pool<<<256, 256, 0, stream>>>(x, logitsT, cf1);
    k3_mha1<<<16, 256, 0, stream>>>(cf1, a1_wq, a1_bq, memory, a1_wk, a1_bk,
                                    a1_wv, a1_bv, a1_fc, a1_fcb,
                                    a1_ln_g, a1_ln_b, cfs);
    k5_proj<<<dim3(2048, 3), 256, 0, stream>>>(w1, cfs, a2_wq, a2_bq, a2_wk, a2_bk,
                                               a2_wv, a2_bv, Qb, Kb, Vt);
    k6_attn<<<1024, 256, 0, stream>>>(Qb, Kb, Vt, aoP0, aoP1, sP0, sP1);
    k7_final<<<1024, 256, 0, stream>>>(aoP0, aoP1, sP0, sP1, w1, cfs, a2_fc, a2_fcb,
                                       a2_ln_g, a2_ln_b, (float*)d_out);
}

// Round 10
// 223.796 us; speedup vs baseline: 1.3666x; 1.1038x over previous
//
#include <hip/hip_runtime.h>
#include <math.h>

typedef unsigned short ushort_t;
typedef __attribute__((ext_vector_type(8))) short short8;
typedef __attribute__((ext_vector_type(4))) float f32x4;

#define B_  16
#define HW_ 1024
#define C_  64
#define NC_ 5
#define D1_ 96
#define NH_ 4
#define DH_ 64

#define MFMA32(A,B,C) __builtin_amdgcn_mfma_f32_16x16x32_bf16(A,B,C,0,0,0)

__device__ __forceinline__ ushort_t f2bf(float f) {
    unsigned u = __float_as_uint(f);
    u = u + 0x7fffu + ((u >> 16) & 1u);   // round-to-nearest-even
    return (ushort_t)(u >> 16);
}

// truncating bf16 pair-pack: one op per 2 elements (lo -> low short, hi -> high short)
__device__ __forceinline__ unsigned pack2_trunc(float lo, float hi) {
    return (__float_as_uint(hi) & 0xffff0000u) | (__float_as_uint(lo) >> 16);
}
__device__ __forceinline__ float bf_lo(unsigned u) { return __uint_as_float(u << 16); }
__device__ __forceinline__ float bf_hi(unsigned u) { return __uint_as_float(u & 0xffff0000u); }

// ---------------- K1: logits = xt @ wb_w + wb_b ; weight1 = softmax over classes ----------------
__global__ __launch_bounds__(64) void k1_logits(const float* __restrict__ x,
                                                const float* __restrict__ wb_w,
                                                const float* __restrict__ wb_b,
                                                float* __restrict__ logitsT,
                                                float* __restrict__ w1) {
    int b = blockIdx.x >> 4;
    int hw = (blockIdx.x & 15) * 64 + threadIdx.x;
    const float* xb = x + (size_t)b * C_ * HW_;
    float acc[NC_];
#pragma unroll
    for (int j = 0; j < NC_; j++) acc[j] = wb_b[j];
#pragma unroll 8
    for (int c = 0; c < C_; c++) {
        float xv = xb[c * HW_ + hw];
#pragma unroll
        for (int j = 0; j < NC_; j++) acc[j] += xv * wb_w[c * NC_ + j];
    }
    float m = acc[0];
#pragma unroll
    for (int j = 1; j < NC_; j++) m = fmaxf(m, acc[j]);
    float e[NC_], s = 0.f;
#pragma unroll
    for (int j = 0; j < NC_; j++) { e[j] = __expf(acc[j] - m); s += e[j]; }
    float inv = 1.f / s;
    int idx = b * HW_ + hw;
#pragma unroll
    for (int j = 0; j < NC_; j++) {
        logitsT[((size_t)b * NC_ + j) * HW_ + hw] = acc[j];
        w1[(size_t)idx * NC_ + j] = e[j] * inv;
    }
}

// ---------------- K2: fused softmax-over-HW + pooling: cf1[b,c,ch] ----------------
__global__ __launch_bounds__(256) void k2b_pool(const float* __restrict__ x,
                                                const float* __restrict__ logitsT,
                                                float* __restrict__ cf1) {
    __shared__ float pl[NC_ * HW_];     // 20 KB
    __shared__ float sinv[NC_];
    int t = threadIdx.x;
    int b = blockIdx.x >> 4, chg = blockIdx.x & 15;
    const float* lp = logitsT + (size_t)b * NC_ * HW_;
    for (int i = t * 4; i < NC_ * HW_; i += 1024)
        *(float4*)(pl + i) = *(const float4*)(lp + i);
    __syncthreads();
    int w = t >> 6, lane = t & 63;
    for (int r = w; r < NC_; r += 4) {
        float m = -1e30f;
        for (int i = lane; i < HW_; i += 64) m = fmaxf(m, pl[r * HW_ + i]);
#pragma unroll
        for (int off = 1; off < 64; off <<= 1) m = fmaxf(m, __shfl_xor(m, off, 64));
        float s = 0.f;
        for (int i = lane; i < HW_; i += 64) {
            float e = __expf(pl[r * HW_ + i] - m);
            pl[r * HW_ + i] = e;
            s += e;
        }
#pragma unroll
        for (int off = 1; off < 64; off <<= 1) s += __shfl_xor(s, off, 64);
        if (lane == 0) sinv[r] = 1.f / s;
    }
    __syncthreads();
    int ch = chg * 4 + w;
    const float* xc = x + ((size_t)b * C_ + ch) * HW_;
    float acc[NC_] = {0.f, 0.f, 0.f, 0.f, 0.f};
#pragma unroll
    for (int i = 0; i < HW_ / 64; i++) {
        int hw = i * 64 + lane;
        float xv = xc[hw];
#pragma unroll
        for (int c = 0; c < NC_; c++) acc[c] += xv * pl[c * HW_ + hw];
    }
#pragma unroll
    for (int c = 0; c < NC_; c++) {
        float a = acc[c];
#pragma unroll
        for (int off = 1; off < 64; off <<= 1) a += __shfl_xor(a, off, 64);
        if (lane == 0) cf1[((size_t)b * NC_ + c) * C_ + ch] = a * sinv[c];
    }
}

// ---------------- K3: MHA1 (n_head=1, dk=96, dv=64) + residual + LN, per batch ----------------
__global__ __launch_bounds__(256) void k3_mha1(const float* __restrict__ cf1,
                                               const float* __restrict__ wq, const float* __restrict__ bq,
                                               const float* __restrict__ mem,
                                               const float* __restrict__ wk, const float* __restrict__ bk,
                                               const float* __restrict__ wv, const float* __restrict__ bv,
                                               const float* __restrict__ fc, const float* __restrict__ fcb,
                                               const float* __restrict__ lng, const float* __restrict__ lnb,
                                               float* __restrict__ cfs) {
    __shared__ float cs[NC_ * C_];
    __shared__ float kh[NC_ * D1_];
    __shared__ float vh[NC_ * DH_];
    __shared__ float q[NC_ * D1_];
    __shared__ float sc[NC_ * NC_];
    __shared__ float pp[NC_ * NC_];
    __shared__ float o[NC_ * C_];
    __shared__ float z[NC_ * C_];
    __shared__ float mu[NC_], rs[NC_];
    int t = threadIdx.x, b = blockIdx.x;
    for (int i = t; i < NC_ * C_; i += 256) cs[i] = cf1[(size_t)b * NC_ * C_ + i];
    for (int idx = t; idx < NC_ * D1_; idx += 256) {
        int i = idx / D1_, k = idx % D1_;
        float a = bk[k];
        for (int d = 0; d < D1_; d++) a += mem[i * D1_ + d] * wk[d * D1_ + k];
        kh[idx] = a;
    }
    for (int idx = t; idx < NC_ * DH_; idx += 256) {
        int i = idx / DH_, dv = idx % DH_;
        float a = bv[dv];
        for (int d = 0; d < D1_; d++) a += mem[i * D1_ + d] * wv[d * DH_ + dv];
        vh[idx] = a;
    }
    __syncthreads();
    for (int idx = t; idx < NC_ * D1_; idx += 256) {
        int i = idx / D1_, k = idx % D1_;
        float a = bq[k];
        for (int c = 0; c < C_; c++) a += cs[i * C_ + c] * wq[c * D1_ + k];
        q[idx] = a;
    }
    __syncthreads();
    if (t < NC_ * NC_) {
        int i = t / NC_, j = t % NC_;
        float a = 0.f;
        for (int k = 0; k < D1_; k++) a += q[i * D1_ + k] * kh[j * D1_ + k];
        sc[t] = a * 0.1020620726159657f;     // 1/sqrt(96)
    }
    __syncthreads();
    if (t < NC_) {
        float m = sc[t * NC_];
        for (int j = 1; j < NC_; j++) m = fmaxf(m, sc[t * NC_ + j]);
        float e[NC_], s = 0.f;
        for (int j = 0; j < NC_; j++) { e[j] = __expf(sc[t * NC_ + j] - m); s += e[j]; }
        float inv = 1.f / s;
        for (int j = 0; j < NC_; j++) pp[t * NC_ + j] = e[j] * inv;
    }
    __syncthreads();
    for (int idx = t; idx < NC_ * C_; idx += 256) {
        int i = idx / C_, dv = idx % C_;
        float a = 0.f;
        for (int j = 0; j < NC_; j++) a += pp[i * NC_ + j] * vh[j * C_ + dv];
        o[idx] = a;
    }
    __syncthreads();
    for (int idx = t; idx < NC_ * C_; idx += 256) {
        int i = idx / C_, dd = idx % C_;
        float a = fcb[dd] + cs[idx];
        for (int c2 = 0; c2 < C_; c2++) a += o[i * C_ + c2] * fc[c2 * C_ + dd];
        z[idx] = a;
    }
    __syncthreads();
    if (t < NC_) {
        float s = 0.f;
        for (int d = 0; d < C_; d++) s += z[t * C_ + d];
        float mm = s / C_;
        float v = 0.f;
        for (int d = 0; d < C_; d++) { float dd2 = z[t * C_ + d] - mm; v += dd2 * dd2; }
        mu[t] = mm; rs[t] = rsqrtf(v / C_ + 1e-6f);
    }
    __syncthreads();
    for (int idx = t; idx < NC_ * C_; idx += 256) {
        int i = idx / C_, dd = idx % C_;
        cfs[(size_t)b * NC_ * C_ + idx] = (z[idx] - mu[i]) * rs[i] * lng[dd] + lnb[dd];
    }
}

// ---------------- K5: inline redistribution (w1·cfs) + Q/K/V projections ----------------
__global__ __launch_bounds__(256) void k5_proj(const float* __restrict__ w1,
                                               const float* __restrict__ cfs,
                                               const float* __restrict__ wq, const float* __restrict__ bq,
                                               const float* __restrict__ wk, const float* __restrict__ bk,
                                               const float* __restrict__ wv, const float* __restrict__ bv,
                                               ushort_t* __restrict__ Qb, ushort_t* __restrict__ Kb,
                                               ushort_t* __restrict__ Vt) {
    __shared__ float rows[8][64];
    int t = threadIdx.x;
    int which = blockIdx.y;
    int m0 = blockIdx.x * 8;
    int b5 = m0 >> 10;
    {
        int ch = t & 63, rr = t >> 6;
        const float* cp = cfs + (size_t)b5 * NC_ * C_;
        for (int r = rr; r < 8; r += 4) {
            const float* w1p = w1 + (size_t)(m0 + r) * NC_;
            float a = 0.f;
#pragma unroll
            for (int c = 0; c < NC_; c++) a += w1p[c] * cp[c * 64 + ch];
            rows[r][ch] = a;
        }
    }
    __syncthreads();
    const float* W = (which == 0) ? wq : (which == 1) ? wk : wv;
    const float* bias = (which == 0) ? bq : (which == 1) ? bk : bv;
    // Q scale = (1/sqrt(64)) * log2(e): k6 uses exp2 directly
    float scale = (which == 0) ? 0.18033688011112042f : 1.0f;
    int c = t;
    float bb = bias[c];
    float acc[8];
#pragma unroll
    for (int r = 0; r < 8; r++) acc[r] = bb;
    for (int k = 0; k < 64; k++) {
        float wv_ = W[k * 256 + c];
#pragma unroll
        for (int r = 0; r < 8; r++) acc[r] += rows[r][k] * wv_;
    }
    int h = c >> 6, dd = c & 63;
    if (which == 2) {
        union { ushort_t s[8]; uint4 u; } pk;
#pragma unroll
        for (int r = 0; r < 8; r++) pk.s[r] = f2bf(acc[r]);
        int l0 = m0 & 1023;
        *(uint4*)(Vt + ((size_t)(b5 * NH_ + h) * DH_ + dd) * HW_ + l0) = pk.u;
    } else {
        ushort_t* dst = (which == 0) ? Qb : Kb;
#pragma unroll
        for (int r = 0; r < 8; r++) {
            int m = m0 + r, b = m >> 10, hw = m & 1023;
            dst[(((size_t)(b * NH_ + h) * HW_) + hw) * DH_ + dd] = f2bf(acc[r] * scale);
        }
    }
}

// ---------------- K6: MFMA bf16 flash attention — split-K2 + 4 q-tiles/wave ----------------
// 8 x 16B loads per iter now feed 36 MFMAs (R9: 18) — total L1 traffic halves to ~256 MB,
// load-inst per FLOP halves. Grid 512 (2 blocks/CU, 8 waves). R5/R7 A/B showed q-tile
// amortization dominates occupancy in this regime. XCD swizzle L%8==bh%8 kept.
__global__ __launch_bounds__(256) void k6_attn(const ushort_t* __restrict__ Qb,
                                               const ushort_t* __restrict__ Kb,
                                               const ushort_t* __restrict__ Vt,
                                               ushort_t* __restrict__ aoP0, ushort_t* __restrict__ aoP1,
                                               float* __restrict__ sP0, float* __restrict__ sP1) {
    int t = threadIdx.x;
    int w = t >> 6;
    int lane = t & 63;
    int l15 = lane & 15;
    int quad = lane >> 4;
    // decode swizzled block id (grid 512): [2:0]=bh_lo, [5:3]=bh_hi, [6]=khalf, [8:7]=qt
    int L = blockIdx.x;
    int bh = ((L >> 3) & 7) * 8 + (L & 7);
    int khalf = (L >> 6) & 1;
    int qt = L >> 7;                     // 0..3
    int b = bh >> 2, h = bh & 3;
    const ushort_t* Qp = Qb + (size_t)bh * HW_ * DH_;
    const ushort_t* Kp = Kb + (size_t)bh * HW_ * DH_;
    const ushort_t* Vp = Vt + (size_t)bh * DH_ * HW_;
    int row0 = qt * 256 + w * 16;        // tiles at row0 + 64*tl
    short8 q0[4], q1[4];
#pragma unroll
    for (int tl = 0; tl < 4; tl++) {
        const ushort_t* qp = Qp + (size_t)(row0 + tl * 64 + l15) * DH_ + quad * 8;
        q0[tl] = *(const short8*)(qp);
        q1[tl] = *(const short8*)(qp + 32);
    }
    // permuted key offsets: S^T tile0 row l15 -> key f0, tile1 -> f0+4
    int f0 = ((l15 >> 2) * 8) + (l15 & 3);
    int kstart = khalf * 512;
    const ushort_t* K0p = Kp + (size_t)(kstart + f0) * DH_ + quad * 8;
    const ushort_t* K1p = Kp + (size_t)(kstart + f0 + 4) * DH_ + quad * 8;
    const ushort_t* Vp0 = Vp + (size_t)(0 * 16 + l15) * HW_ + kstart + quad * 8;
    const ushort_t* Vp1 = Vp + (size_t)(1 * 16 + l15) * HW_ + kstart + quad * 8;
    const ushort_t* Vp2 = Vp + (size_t)(2 * 16 + l15) * HW_ + kstart + quad * 8;
    const ushort_t* Vp3 = Vp + (size_t)(3 * 16 + l15) * HW_ + kstart + quad * 8;
    const short ONE = (short)0x3F80;      // bf16 1.0
    short8 ones = {ONE, ONE, ONE, ONE, ONE, ONE, ONE, ONE};
    f32x4 o0[4], o1[4], o2[4], o3[4], oS[4];
#pragma unroll
    for (int tl = 0; tl < 4; tl++) {
        o0[tl] = (f32x4){0,0,0,0}; o1[tl] = (f32x4){0,0,0,0};
        o2[tl] = (f32x4){0,0,0,0}; o3[tl] = (f32x4){0,0,0,0};
        oS[tl] = (f32x4){0,0,0,0};
    }
    for (int kt = 0; kt < 16; kt++) {
        int kbase = kt * 32;
        size_t koff = (size_t)kbase * DH_;
        short8 ka0 = *(const short8*)(K0p + koff);
        short8 ka1 = *(const short8*)(K0p + koff + 32);
        short8 kb0 = *(const short8*)(K1p + koff);
        short8 kb1 = *(const short8*)(K1p + koff + 32);
        short8 v0 = *(const short8*)(Vp0 + kbase);
        short8 v1 = *(const short8*)(Vp1 + kbase);
        short8 v2 = *(const short8*)(Vp2 + kbase);
        short8 v3 = *(const short8*)(Vp3 + kbase);
        f32x4 z = {0,0,0,0};
#pragma unroll
        for (int tl = 0; tl < 4; tl++) {
            f32x4 s0 = MFMA32(ka0, q0[tl], z);  s0 = MFMA32(ka1, q1[tl], s0);
            f32x4 s1 = MFMA32(kb0, q0[tl], z);  s1 = MFMA32(kb1, q1[tl], s1);
            float p0 = exp2f(s0[0]), p1 = exp2f(s0[1]), p2 = exp2f(s0[2]), p3 = exp2f(s0[3]);
            float p4 = exp2f(s1[0]), p5 = exp2f(s1[1]), p6 = exp2f(s1[2]), p7 = exp2f(s1[3]);
            union { short8 v; unsigned u[4]; } pf;
            pf.u[0] = pack2_trunc(p0, p1);  pf.u[1] = pack2_trunc(p2, p3);
            pf.u[2] = pack2_trunc(p4, p5);  pf.u[3] = pack2_trunc(p6, p7);
            o0[tl] = MFMA32(v0, pf.v, o0[tl]);
            o1[tl] = MFMA32(v1, pf.v, o1[tl]);
            o2[tl] = MFMA32(v2, pf.v, o2[tl]);
            o3[tl] = MFMA32(v3, pf.v, o3[tl]);
            oS[tl] = MFMA32(ones, pf.v, oS[tl]);
        }
    }
    ushort_t* aoP = khalf ? aoP1 : aoP0;
    float* sP = khalf ? sP1 : sP0;
#pragma unroll
    for (int tl = 0; tl < 4; tl++) {
        int rowg = row0 + tl * 64 + l15;
        ushort_t* aop = aoP + ((size_t)(b * HW_ + rowg)) * 256 + h * 64 + quad * 4;
        uint2 u;
        u.x = pack2_trunc(o0[tl][0], o0[tl][1]); u.y = pack2_trunc(o0[tl][2], o0[tl][3]);
        *(uint2*)(aop + 0) = u;
        u.x = pack2_trunc(o1[tl][0], o1[tl][1]); u.y = pack2_trunc(o1[tl][2], o1[tl][3]);
        *(uint2*)(aop + 16) = u;
        u.x = pack2_trunc(o2[tl][0], o2[tl][1]); u.y = pack2_trunc(o2[tl][2], o2[tl][3]);
        *(uint2*)(aop + 32) = u;
        u.x = pack2_trunc(o3[tl][0], o3[tl][1]); u.y = pack2_trunc(o3[tl][2], o3[tl][3]);
        *(uint2*)(aop + 48) = u;
        if (quad == 0)
            sP[(size_t)(b * HW_ + rowg) * NH_ + h] = oS[tl][0];
    }
}

// ---------------- K7: combine bf16 partials + inline residual (w1·cfs) + fc + LN ----------------
__global__ __launch_bounds__(256) void k7_final(const ushort_t* __restrict__ aoP0,
                                                const ushort_t* __restrict__ aoP1,
                                                const float* __restrict__ sP0,
                                                const float* __restrict__ sP1,
                                                const float* __restrict__ w1,
                                                const float* __restrict__ cfs,
                                                const float* __restrict__ fc, const float* __restrict__ fcb,
                                                const float* __restrict__ lng, const float* __restrict__ lnb,
                                                float* __restrict__ out) {
    __shared__ float srow[16 * 256];      // 16 KB
    __shared__ float rinv[64];            // per (row, head) 1/(s0+s1)
    __shared__ float T[64 * 17];          // padded transpose buffer
    int t = threadIdx.x, w = t >> 6, d = t & 63;
    int m0 = blockIdx.x * 16;
    int b = m0 >> 10;
    if (t < 64) {
        int row = t >> 2, hh = t & 3;
        float s = sP0[(size_t)(m0 + row) * NH_ + hh] + sP1[(size_t)(m0 + row) * NH_ + hh];
        rinv[t] = 1.f / s;
    }
    __syncthreads();
    for (int i = t; i < 512; i += 256) {          // 512 chunks of 8 bf16 elements
        uint4 a  = *(const uint4*)(aoP0 + (size_t)m0 * 256 + i * 8);
        uint4 c4 = *(const uint4*)(aoP1 + (size_t)m0 * 256 + i * 8);
        int e = i * 8, row = e >> 8, hh = (e >> 6) & 3;
        float r = rinv[row * 4 + hh];
        srow[e + 0] = (bf_lo(a.x) + bf_lo(c4.x)) * r;
        srow[e + 1] = (bf_hi(a.x) + bf_hi(c4.x)) * r;
        srow[e + 2] = (bf_lo(a.y) + bf_lo(c4.y)) * r;
        srow[e + 3] = (bf_hi(a.y) + bf_hi(c4.y)) * r;
        srow[e + 4] = (bf_lo(a.z) + bf_lo(c4.z)) * r;
        srow[e + 5] = (bf_hi(a.z) + bf_hi(c4.z)) * r;
        srow[e + 6] = (bf_lo(a.w) + bf_lo(c4.w)) * r;
        srow[e + 7] = (bf_hi(a.w) + bf_hi(c4.w)) * r;
    }
    __syncthreads();
    float bias = fcb[d];
    const float* cp = cfs + (size_t)b * NC_ * C_;
    float a[4];
#pragma unroll
    for (int j = 0; j < 4; j++) {
        int m = m0 + w * 4 + j;
        const float* w1p = w1 + (size_t)m * NC_;
        float acc = bias;
#pragma unroll
        for (int c = 0; c < NC_; c++) acc += w1p[c] * cp[c * 64 + d];   // inline redistribution
        a[j] = acc;
    }
#pragma unroll 8
    for (int k = 0; k < 256; k++) {
        float f = fc[k * 64 + d];
#pragma unroll
        for (int j = 0; j < 4; j++) a[j] += srow[(w * 4 + j) * 256 + k] * f;
    }
    float g = lng[d], be = lnb[d];
#pragma unroll
    for (int j = 0; j < 4; j++) {
        float s1 = a[j], s2 = a[j] * a[j];
#pragma unroll
        for (int off = 1; off < 64; off <<= 1) {
            s1 += __shfl_xor(s1, off, 64);
            s2 += __shfl_xor(s2, off, 64);
        }
        float mu = s1 * (1.f / 64.f);
        float var = s2 * (1.f / 64.f) - mu * mu;
        float rstd = rsqrtf(var + 1e-6f);
        T[d * 17 + w * 4 + j] = (a[j] - mu) * rstd * g + be;
    }
    __syncthreads();
    int ch = t >> 2, part = t & 3;
    int hw0 = m0 & 1023;
    float4 v = {T[ch * 17 + part * 4 + 0], T[ch * 17 + part * 4 + 1],
                T[ch * 17 + part * 4 + 2], T[ch * 17 + part * 4 + 3]};
    *(float4*)&out[((size_t)b * 64 + ch) * 1024 + hw0 + part * 4] = v;
}

// ---------------- launcher: 6 dispatches ----------------
extern "C" void kernel_launch(void* const* d_in, const int* in_sizes, int n_in,
                              void* d_out, int out_size, void* d_ws, size_t ws_size,
                              hipStream_t stream) {
    const float* x      = (const float*)d_in[0];
    const float* memory = (const float*)d_in[1];
    const float* wb_w   = (const float*)d_in[2];
    const float* wb_b   = (const float*)d_in[3];
    const float* a1_wq  = (const float*)d_in[4];
    const float* a1_bq  = (const float*)d_in[5];
    const float* a1_wk  = (const float*)d_in[6];
    const float* a1_bk  = (const float*)d_in[7];
    const float* a1_wv  = (const float*)d_in[8];
    const float* a1_bv  = (const float*)d_in[9];
    const float* a1_fc  = (const float*)d_in[10];
    const float* a1_fcb = (const float*)d_in[11];
    const float* a1_ln_g = (const float*)d_in[12];
    const float* a1_ln_b = (const float*)d_in[13];
    const float* a2_wq  = (const float*)d_in[14];
    const float* a2_bq  = (const float*)d_in[15];
    const float* a2_wk  = (const float*)d_in[16];
    const float* a2_bk  = (const float*)d_in[17];
    const float* a2_wv  = (const float*)d_in[18];
    const float* a2_bv  = (const float*)d_in[19];
    const float* a2_fc  = (const float*)d_in[20];
    const float* a2_fcb = (const float*)d_in[21];
    const float* a2_ln_g = (const float*)d_in[22];
    const float* a2_ln_b = (const float*)d_in[23];

    float* ws = (float*)d_ws;
    float* logitsT = ws;                                   // 81920 f
    float* w1  = logitsT + 81920;                          // 81920 f
    float* cf1 = w1 + 81920;                               // 5120 f
    float* cfs = cf1 + 5120;                               // 5120 f
    float* sP0 = cfs + 5120;                               // 65536 f
    float* sP1 = sP0 + 65536;                              // 65536 f
    ushort_t* aoP0 = (ushort_t*)(sP1 + 65536);             // 4,194,304 ushorts each
    ushort_t* aoP1 = aoP0 + 4194304;
    ushort_t* Qb = aoP1 + 4194304;
    ushort_t* Kb = Qb + 4194304;
    ushort_t* Vt = Kb + 4194304;                           // total ~43 MB

    k1_logits<<<256, 64, 0, stream>>>(x, wb_w, wb_b, logitsT, w1);
    k2b_pool<<<256, 256, 0, stream>>>(x, logitsT, cf1);
    k3_mha1<<<16, 256, 0, stream>>>(cf1, a1_wq, a1_bq, memory, a1_wk, a1_bk,
                                    a1_wv, a1_bv, a1_fc, a1_fcb,
                                    a1_ln_g, a1_ln_b, cfs);
    k5_proj<<<dim3(2048, 3), 256, 0, stream>>>(w1, cfs, a2_wq, a2_bq, a2_wk, a2_bk,
                                               a2_wv, a2_bv, Qb, Kb, Vt);
    k6_attn<<<512, 256, 0, stream>>>(Qb, Kb, Vt, aoP0, aoP1, sP0, sP1);
    k7_final<<<1024, 256, 0, stream>>>(aoP0, aoP1, sP0, sP1, w1, cfs, a2_fc, a2_fcb,
                                       a2_ln_g, a2_ln_b, (float*)d_out);
}

// Round 11
// 202.530 us; speedup vs baseline: 1.5101x; 1.1050x over previous
//
#include <hip/hip_runtime.h>
#include <math.h>

typedef unsigned short ushort_t;
typedef __attribute__((ext_vector_type(8))) short short8;
typedef __attribute__((ext_vector_type(4))) float f32x4;

#define B_  16
#define HW_ 1024
#define C_  64
#define NC_ 5
#define D1_ 96
#define NH_ 4
#define DH_ 64

#define MFMA32(A,B,C) __builtin_amdgcn_mfma_f32_16x16x32_bf16(A,B,C,0,0,0)

__device__ __forceinline__ ushort_t f2bf(float f) {
    unsigned u = __float_as_uint(f);
    u = u + 0x7fffu + ((u >> 16) & 1u);   // round-to-nearest-even
    return (ushort_t)(u >> 16);
}

// truncating bf16 pair-pack: one op per 2 elements (lo -> low short, hi -> high short)
__device__ __forceinline__ unsigned pack2_trunc(float lo, float hi) {
    return (__float_as_uint(hi) & 0xffff0000u) | (__float_as_uint(lo) >> 16);
}
__device__ __forceinline__ unsigned pack2_rne(float lo, float hi) {
    return ((unsigned)f2bf(hi) << 16) | (unsigned)f2bf(lo);
}
__device__ __forceinline__ float bf_lo(unsigned u) { return __uint_as_float(u << 16); }
__device__ __forceinline__ float bf_hi(unsigned u) { return __uint_as_float(u & 0xffff0000u); }

// ---------------- K1: logits = xt @ wb_w + wb_b ; weight1 = softmax over classes ----------------
__global__ __launch_bounds__(64) void k1_logits(const float* __restrict__ x,
                                                const float* __restrict__ wb_w,
                                                const float* __restrict__ wb_b,
                                                float* __restrict__ logitsT,
                                                float* __restrict__ w1) {
    int b = blockIdx.x >> 4;
    int hw = (blockIdx.x & 15) * 64 + threadIdx.x;
    const float* xb = x + (size_t)b * C_ * HW_;
    float acc[NC_];
#pragma unroll
    for (int j = 0; j < NC_; j++) acc[j] = wb_b[j];
#pragma unroll 8
    for (int c = 0; c < C_; c++) {
        float xv = xb[c * HW_ + hw];
#pragma unroll
        for (int j = 0; j < NC_; j++) acc[j] += xv * wb_w[c * NC_ + j];
    }
    float m = acc[0];
#pragma unroll
    for (int j = 1; j < NC_; j++) m = fmaxf(m, acc[j]);
    float e[NC_], s = 0.f;
#pragma unroll
    for (int j = 0; j < NC_; j++) { e[j] = __expf(acc[j] - m); s += e[j]; }
    float inv = 1.f / s;
    int idx = b * HW_ + hw;
#pragma unroll
    for (int j = 0; j < NC_; j++) {
        logitsT[((size_t)b * NC_ + j) * HW_ + hw] = acc[j];
        w1[(size_t)idx * NC_ + j] = e[j] * inv;
    }
}

// ---------------- K2: fused softmax-over-HW + pooling: cf1[b,c,ch] ----------------
__global__ __launch_bounds__(256) void k2b_pool(const float* __restrict__ x,
                                                const float* __restrict__ logitsT,
                                                float* __restrict__ cf1) {
    __shared__ float pl[NC_ * HW_];     // 20 KB
    __shared__ float sinv[NC_];
    int t = threadIdx.x;
    int b = blockIdx.x >> 4, chg = blockIdx.x & 15;
    const float* lp = logitsT + (size_t)b * NC_ * HW_;
    for (int i = t * 4; i < NC_ * HW_; i += 1024)
        *(float4*)(pl + i) = *(const float4*)(lp + i);
    __syncthreads();
    int w = t >> 6, lane = t & 63;
    for (int r = w; r < NC_; r += 4) {
        float m = -1e30f;
        for (int i = lane; i < HW_; i += 64) m = fmaxf(m, pl[r * HW_ + i]);
#pragma unroll
        for (int off = 1; off < 64; off <<= 1) m = fmaxf(m, __shfl_xor(m, off, 64));
        float s = 0.f;
        for (int i = lane; i < HW_; i += 64) {
            float e = __expf(pl[r * HW_ + i] - m);
            pl[r * HW_ + i] = e;
            s += e;
        }
#pragma unroll
        for (int off = 1; off < 64; off <<= 1) s += __shfl_xor(s, off, 64);
        if (lane == 0) sinv[r] = 1.f / s;
    }
    __syncthreads();
    int ch = chg * 4 + w;
    const float* xc = x + ((size_t)b * C_ + ch) * HW_;
    float acc[NC_] = {0.f, 0.f, 0.f, 0.f, 0.f};
#pragma unroll
    for (int i = 0; i < HW_ / 64; i++) {
        int hw = i * 64 + lane;
        float xv = xc[hw];
#pragma unroll
        for (int c = 0; c < NC_; c++) acc[c] += xv * pl[c * HW_ + hw];
    }
#pragma unroll
    for (int c = 0; c < NC_; c++) {
        float a = acc[c];
#pragma unroll
        for (int off = 1; off < 64; off <<= 1) a += __shfl_xor(a, off, 64);
        if (lane == 0) cf1[((size_t)b * NC_ + c) * C_ + ch] = a * sinv[c];
    }
}

// ---------------- K3: MHA1 (n_head=1, dk=96, dv=64) + residual + LN, per batch ----------------
__global__ __launch_bounds__(256) void k3_mha1(const float* __restrict__ cf1,
                                               const float* __restrict__ wq, const float* __restrict__ bq,
                                               const float* __restrict__ mem,
                                               const float* __restrict__ wk, const float* __restrict__ bk,
                                               const float* __restrict__ wv, const float* __restrict__ bv,
                                               const float* __restrict__ fc, const float* __restrict__ fcb,
                                               const float* __restrict__ lng, const float* __restrict__ lnb,
                                               float* __restrict__ cfs) {
    __shared__ float cs[NC_ * C_];
    __shared__ float kh[NC_ * D1_];
    __shared__ float vh[NC_ * DH_];
    __shared__ float q[NC_ * D1_];
    __shared__ float sc[NC_ * NC_];
    __shared__ float pp[NC_ * NC_];
    __shared__ float o[NC_ * C_];
    __shared__ float z[NC_ * C_];
    __shared__ float mu[NC_], rs[NC_];
    int t = threadIdx.x, b = blockIdx.x;
    for (int i = t; i < NC_ * C_; i += 256) cs[i] = cf1[(size_t)b * NC_ * C_ + i];
    for (int idx = t; idx < NC_ * D1_; idx += 256) {
        int i = idx / D1_, k = idx % D1_;
        float a = bk[k];
        for (int d = 0; d < D1_; d++) a += mem[i * D1_ + d] * wk[d * D1_ + k];
        kh[idx] = a;
    }
    for (int idx = t; idx < NC_ * DH_; idx += 256) {
        int i = idx / DH_, dv = idx % DH_;
        float a = bv[dv];
        for (int d = 0; d < D1_; d++) a += mem[i * D1_ + d] * wv[d * DH_ + dv];
        vh[idx] = a;
    }
    __syncthreads();
    for (int idx = t; idx < NC_ * D1_; idx += 256) {
        int i = idx / D1_, k = idx % D1_;
        float a = bq[k];
        for (int c = 0; c < C_; c++) a += cs[i * C_ + c] * wq[c * D1_ + k];
        q[idx] = a;
    }
    __syncthreads();
    if (t < NC_ * NC_) {
        int i = t / NC_, j = t % NC_;
        float a = 0.f;
        for (int k = 0; k < D1_; k++) a += q[i * D1_ + k] * kh[j * D1_ + k];
        sc[t] = a * 0.1020620726159657f;     // 1/sqrt(96)
    }
    __syncthreads();
    if (t < NC_) {
        float m = sc[t * NC_];
        for (int j = 1; j < NC_; j++) m = fmaxf(m, sc[t * NC_ + j]);
        float e[NC_], s = 0.f;
        for (int j = 0; j < NC_; j++) { e[j] = __expf(sc[t * NC_ + j] - m); s += e[j]; }
        float inv = 1.f / s;
        for (int j = 0; j < NC_; j++) pp[t * NC_ + j] = e[j] * inv;
    }
    __syncthreads();
    for (int idx = t; idx < NC_ * C_; idx += 256) {
        int i = idx / C_, dv = idx % C_;
        float a = 0.f;
        for (int j = 0; j < NC_; j++) a += pp[i * NC_ + j] * vh[j * C_ + dv];
        o[idx] = a;
    }
    __syncthreads();
    for (int idx = t; idx < NC_ * C_; idx += 256) {
        int i = idx / C_, dd = idx % C_;
        float a = fcb[dd] + cs[idx];
        for (int c2 = 0; c2 < C_; c2++) a += o[i * C_ + c2] * fc[c2 * C_ + dd];
        z[idx] = a;
    }
    __syncthreads();
    if (t < NC_) {
        float s = 0.f;
        for (int d = 0; d < C_; d++) s += z[t * C_ + d];
        float mm = s / C_;
        float v = 0.f;
        for (int d = 0; d < C_; d++) { float dd2 = z[t * C_ + d] - mm; v += dd2 * dd2; }
        mu[t] = mm; rs[t] = rsqrtf(v / C_ + 1e-6f);
    }
    __syncthreads();
    for (int idx = t; idx < NC_ * C_; idx += 256) {
        int i = idx / C_, dd = idx % C_;
        cfs[(size_t)b * NC_ * C_ + idx] = (z[idx] - mu[i]) * rs[i] * lng[dd] + lnb[dd];
    }
}

// ---------------- K5: MFMA projection GEMM (inline redistribution + Q/K/V) ----------------
// grid (256, 3): block = 64 rows of one batch x one `which`. Stage cf rows bf16 Af[64][68]
// and transposed weights Wt[256][68] in LDS (pad 68 -> 2-way bank aliasing, free).
// Q/K: D[l][n] = MFMA(A=Af, B=Wt). V: D[n][l] = MFMA(A=Wt, B=Af) -> writes Vt directly.
// Fragment recipe identical to k6 (validated): lane(l15,quad) holds [l15][quad*8+j], +32.
__global__ __launch_bounds__(256) void k5_mfma(const float* __restrict__ w1,
                                               const float* __restrict__ cfs,
                                               const float* __restrict__ wq, const float* __restrict__ bq,
                                               const float* __restrict__ wk, const float* __restrict__ bk,
                                               const float* __restrict__ wv, const float* __restrict__ bv,
                                               ushort_t* __restrict__ Qb, ushort_t* __restrict__ Kb,
                                               ushort_t* __restrict__ Vt) {
    __shared__ ushort_t Af[64][68];      // cf rows, bf16
    __shared__ ushort_t Wt[256][68];     // W^T [n][k], bf16
    int t = threadIdx.x;
    int which = blockIdx.y;
    int m0 = blockIdx.x * 64;
    int b = m0 >> 10, lbase = m0 & 1023;
    // stage Af: cf[row][k] = sum_c w1[row][c] * cfs[b][c][k]
    {
        int r = t >> 2, ks = (t & 3) * 16;
        const float* cp = cfs + (size_t)b * NC_ * C_;
        const float* w1p = w1 + (size_t)(m0 + r) * NC_;
        float v0 = w1p[0], v1 = w1p[1], v2 = w1p[2], v3 = w1p[3], v4 = w1p[4];
#pragma unroll
        for (int j = 0; j < 16; j += 2) {
            int k = ks + j;
            float e0 = v0 * cp[k]       + v1 * cp[64 + k]     + v2 * cp[128 + k]
                     + v3 * cp[192 + k] + v4 * cp[256 + k];
            float e1 = v0 * cp[k + 1]     + v1 * cp[64 + k + 1] + v2 * cp[128 + k + 1]
                     + v3 * cp[192 + k + 1] + v4 * cp[256 + k + 1];
            *(unsigned*)&Af[r][k] = pack2_rne(e0, e1);
        }
    }
    const float* W = (which == 0) ? wq : (which == 1) ? wk : wv;
    {
        int n = t;
#pragma unroll
        for (int k = 0; k < 64; k += 2) {
            *(unsigned*)&Wt[n][k] = pack2_rne(W[k * 256 + n], W[(k + 1) * 256 + n]);
        }
    }
    __syncthreads();
    int lane = t & 63, w = t >> 6;
    int l15 = lane & 15, quad = lane >> 4;
    if (which < 2) {
        const float* bias = (which == 0) ? bq : bk;
        float scale = (which == 0) ? 0.18033688011112042f : 1.0f;  // log2e/8 folded into Q
        ushort_t* dst = (which == 0) ? Qb : Kb;
        short8 a0[4], a1[4];
#pragma unroll
        for (int mi = 0; mi < 4; mi++) {
            a0[mi] = *(const short8*)&Af[mi * 16 + l15][quad * 8];
            a1[mi] = *(const short8*)&Af[mi * 16 + l15][32 + quad * 8];
        }
#pragma unroll
        for (int nt = 0; nt < 4; nt++) {
            int ni = w * 4 + nt;
            short8 b0 = *(const short8*)&Wt[ni * 16 + l15][quad * 8];
            short8 b1 = *(const short8*)&Wt[ni * 16 + l15][32 + quad * 8];
            int n = ni * 16 + l15;
            float bb = bias[n];
            int h = n >> 6, dd = n & 63;
#pragma unroll
            for (int mi = 0; mi < 4; mi++) {
                f32x4 z = {0, 0, 0, 0};
                f32x4 dv4 = MFMA32(a0[mi], b0, z);
                dv4 = MFMA32(a1[mi], b1, dv4);
                size_t base = ((size_t)(b * NH_ + h) * HW_ + (lbase + mi * 16 + quad * 4)) * DH_ + dd;
#pragma unroll
                for (int r = 0; r < 4; r++)
                    dst[base + (size_t)r * DH_] = f2bf((dv4[r] + bb) * scale);
            }
        }
    } else {
        // V: D[nw][l] = sum_k W[k][nw]*cf[l][k] -> Vt[b,h,dv,l] directly
        short8 a0[4], a1[4];
#pragma unroll
        for (int mt = 0; mt < 4; mt++) {
            int mi = w * 4 + mt;
            a0[mt] = *(const short8*)&Wt[mi * 16 + l15][quad * 8];
            a1[mt] = *(const short8*)&Wt[mi * 16 + l15][32 + quad * 8];
        }
#pragma unroll
        for (int nt = 0; nt < 4; nt++) {
            short8 b0 = *(const short8*)&Af[nt * 16 + l15][quad * 8];
            short8 b1 = *(const short8*)&Af[nt * 16 + l15][32 + quad * 8];
#pragma unroll
            for (int mt = 0; mt < 4; mt++) {
                int mi = w * 4 + mt;
                f32x4 z = {0, 0, 0, 0};
                f32x4 dv4 = MFMA32(a0[mt], b0, z);
                dv4 = MFMA32(a1[mt], b1, dv4);
                int h = mi >> 2;
#pragma unroll
                for (int r = 0; r < 4; r++) {
                    int nw = mi * 16 + quad * 4 + r;
                    int dv = nw & 63;
                    Vt[((size_t)(b * NH_ + h) * DH_ + dv) * HW_ + lbase + nt * 16 + l15] =
                        f2bf(dv4[r] + bv[nw]);
                }
            }
        }
    }
}

// ---------------- K6: MFMA bf16 flash attention — split-K2 + 4 q-tiles/wave ----------------
__global__ __launch_bounds__(256) void k6_attn(const ushort_t* __restrict__ Qb,
                                               const ushort_t* __restrict__ Kb,
                                               const ushort_t* __restrict__ Vt,
                                               ushort_t* __restrict__ aoP0, ushort_t* __restrict__ aoP1,
                                               float* __restrict__ sP0, float* __restrict__ sP1) {
    int t = threadIdx.x;
    int w = t >> 6;
    int lane = t & 63;
    int l15 = lane & 15;
    int quad = lane >> 4;
    // decode swizzled block id (grid 512): [2:0]=bh_lo, [5:3]=bh_hi, [6]=khalf, [8:7]=qt
    int L = blockIdx.x;
    int bh = ((L >> 3) & 7) * 8 + (L & 7);
    int khalf = (L >> 6) & 1;
    int qt = L >> 7;                     // 0..3
    int b = bh >> 2, h = bh & 3;
    const ushort_t* Qp = Qb + (size_t)bh * HW_ * DH_;
    const ushort_t* Kp = Kb + (size_t)bh * HW_ * DH_;
    const ushort_t* Vp = Vt + (size_t)bh * DH_ * HW_;
    int row0 = qt * 256 + w * 16;        // tiles at row0 + 64*tl
    short8 q0[4], q1[4];
#pragma unroll
    for (int tl = 0; tl < 4; tl++) {
        const ushort_t* qp = Qp + (size_t)(row0 + tl * 64 + l15) * DH_ + quad * 8;
        q0[tl] = *(const short8*)(qp);
        q1[tl] = *(const short8*)(qp + 32);
    }
    // permuted key offsets: S^T tile0 row l15 -> key f0, tile1 -> f0+4
    int f0 = ((l15 >> 2) * 8) + (l15 & 3);
    int kstart = khalf * 512;
    const ushort_t* K0p = Kp + (size_t)(kstart + f0) * DH_ + quad * 8;
    const ushort_t* K1p = Kp + (size_t)(kstart + f0 + 4) * DH_ + quad * 8;
    const ushort_t* Vp0 = Vp + (size_t)(0 * 16 + l15) * HW_ + kstart + quad * 8;
    const ushort_t* Vp1 = Vp + (size_t)(1 * 16 + l15) * HW_ + kstart + quad * 8;
    const ushort_t* Vp2 = Vp + (size_t)(2 * 16 + l15) * HW_ + kstart + quad * 8;
    const ushort_t* Vp3 = Vp + (size_t)(3 * 16 + l15) * HW_ + kstart + quad * 8;
    const short ONE = (short)0x3F80;      // bf16 1.0
    short8 ones = {ONE, ONE, ONE, ONE, ONE, ONE, ONE, ONE};
    f32x4 o0[4], o1[4], o2[4], o3[4], oS[4];
#pragma unroll
    for (int tl = 0; tl < 4; tl++) {
        o0[tl] = (f32x4){0,0,0,0}; o1[tl] = (f32x4){0,0,0,0};
        o2[tl] = (f32x4){0,0,0,0}; o3[tl] = (f32x4){0,0,0,0};
        oS[tl] = (f32x4){0,0,0,0};
    }
    for (int kt = 0; kt < 16; kt++) {
        int kbase = kt * 32;
        size_t koff = (size_t)kbase * DH_;
        short8 ka0 = *(const short8*)(K0p + koff);
        short8 ka1 = *(const short8*)(K0p + koff + 32);
        short8 kb0 = *(const short8*)(K1p + koff);
        short8 kb1 = *(const short8*)(K1p + koff + 32);
        short8 v0 = *(const short8*)(Vp0 + kbase);
        short8 v1 = *(const short8*)(Vp1 + kbase);
        short8 v2 = *(const short8*)(Vp2 + kbase);
        short8 v3 = *(const short8*)(Vp3 + kbase);
        f32x4 z = {0,0,0,0};
#pragma unroll
        for (int tl = 0; tl < 4; tl++) {
            f32x4 s0 = MFMA32(ka0, q0[tl], z);  s0 = MFMA32(ka1, q1[tl], s0);
            f32x4 s1 = MFMA32(kb0, q0[tl], z);  s1 = MFMA32(kb1, q1[tl], s1);
            float p0 = exp2f(s0[0]), p1 = exp2f(s0[1]), p2 = exp2f(s0[2]), p3 = exp2f(s0[3]);
            float p4 = exp2f(s1[0]), p5 = exp2f(s1[1]), p6 = exp2f(s1[2]), p7 = exp2f(s1[3]);
            union { short8 v; unsigned u[4]; } pf;
            pf.u[0] = pack2_trunc(p0, p1);  pf.u[1] = pack2_trunc(p2, p3);
            pf.u[2] = pack2_trunc(p4, p5);  pf.u[3] = pack2_trunc(p6, p7);
            o0[tl] = MFMA32(v0, pf.v, o0[tl]);
            o1[tl] = MFMA32(v1, pf.v, o1[tl]);
            o2[tl] = MFMA32(v2, pf.v, o2[tl]);
            o3[tl] = MFMA32(v3, pf.v, o3[tl]);
            oS[tl] = MFMA32(ones, pf.v, oS[tl]);
        }
    }
    ushort_t* aoP = khalf ? aoP1 : aoP0;
    float* sP = khalf ? sP1 : sP0;
#pragma unroll
    for (int tl = 0; tl < 4; tl++) {
        int rowg = row0 + tl * 64 + l15;
        ushort_t* aop = aoP + ((size_t)(b * HW_ + rowg)) * 256 + h * 64 + quad * 4;
        uint2 u;
        u.x = pack2_trunc(o0[tl][0], o0[tl][1]); u.y = pack2_trunc(o0[tl][2], o0[tl][3]);
        *(uint2*)(aop + 0) = u;
        u.x = pack2_trunc(o1[tl][0], o1[tl][1]); u.y = pack2_trunc(o1[tl][2], o1[tl][3]);
        *(uint2*)(aop + 16) = u;
        u.x = pack2_trunc(o2[tl][0], o2[tl][1]); u.y = pack2_trunc(o2[tl][2], o2[tl][3]);
        *(uint2*)(aop + 32) = u;
        u.x = pack2_trunc(o3[tl][0], o3[tl][1]); u.y = pack2_trunc(o3[tl][2], o3[tl][3]);
        *(uint2*)(aop + 48) = u;
        if (quad == 0)
            sP[(size_t)(b * HW_ + rowg) * NH_ + h] = oS[tl][0];
    }
}

// ---------------- K7: combine bf16 partials + inline residual (w1·cfs) + fc + LN ----------------
__global__ __launch_bounds__(256) void k7_final(const ushort_t* __restrict__ aoP0,
                                                const ushort_t* __restrict__ aoP1,
                                                const float* __restrict__ sP0,
                                                const float* __restrict__ sP1,
                                                const float* __restrict__ w1,
                                                const float* __restrict__ cfs,
                                                const float* __restrict__ fc, const float* __restrict__ fcb,
                                                const float* __restrict__ lng, const float* __restrict__ lnb,
                                                float* __restrict__ out) {
    __shared__ float srow[16 * 256];      // 16 KB
    __shared__ float rinv[64];            // per (row, head) 1/(s0+s1)
    __shared__ float T[64 * 17];          // padded transpose buffer
    int t = threadIdx.x, w = t >> 6, d = t & 63;
    int m0 = blockIdx.x * 16;
    int b = m0 >> 10;
    if (t < 64) {
        int row = t >> 2, hh = t & 3;
        float s = sP0[(size_t)(m0 + row) * NH_ + hh] + sP1[(size_t)(m0 + row) * NH_ + hh];
        rinv[t] = 1.f / s;
    }
    __syncthreads();
    for (int i = t; i < 512; i += 256) {          // 512 chunks of 8 bf16 elements
        uint4 a  = *(const uint4*)(aoP0 + (size_t)m0 * 256 + i * 8);
        uint4 c4 = *(const uint4*)(aoP1 + (size_t)m0 * 256 + i * 8);
        int e = i * 8, row = e >> 8, hh = (e >> 6) & 3;
        float r = rinv[row * 4 + hh];
        srow[e + 0] = (bf_lo(a.x) + bf_lo(c4.x)) * r;
        srow[e + 1] = (bf_hi(a.x) + bf_hi(c4.x)) * r;
        srow[e + 2] = (bf_lo(a.y) + bf_lo(c4.y)) * r;
        srow[e + 3] = (bf_hi(a.y) + bf_hi(c4.y)) * r;
        srow[e + 4] = (bf_lo(a.z) + bf_lo(c4.z)) * r;
        srow[e + 5] = (bf_hi(a.z) + bf_hi(c4.z)) * r;
        srow[e + 6] = (bf_lo(a.w) + bf_lo(c4.w)) * r;
        srow[e + 7] = (bf_hi(a.w) + bf_hi(c4.w)) * r;
    }
    __syncthreads();
    float bias = fcb[d];
    const float* cp = cfs + (size_t)b * NC_ * C_;
    float a[4];
#pragma unroll
    for (int j = 0; j < 4; j++) {
        int m = m0 + w * 4 + j;
        const float* w1p = w1 + (size_t)m * NC_;
        float acc = bias;
#pragma unroll
        for (int c = 0; c < NC_; c++) acc += w1p[c] * cp[c * 64 + d];   // inline redistribution
        a[j] = acc;
    }
#pragma unroll 4
    for (int k4 = 0; k4 < 64; k4++) {
        int k = k4 * 4;
        float f0 = fc[(k + 0) * 64 + d];
        float f1 = fc[(k + 1) * 64 + d];
        float f2 = fc[(k + 2) * 64 + d];
        float f3 = fc[(k + 3) * 64 + d];
#pragma unroll
        for (int j = 0; j < 4; j++) {
            float4 s = *(const float4*)&srow[(w * 4 + j) * 256 + k];
            a[j] += s.x * f0 + s.y * f1 + s.z * f2 + s.w * f3;
        }
    }
    float g = lng[d], be = lnb[d];
#pragma unroll
    for (int j = 0; j < 4; j++) {
        float s1 = a[j], s2 = a[j] * a[j];
#pragma unroll
        for (int off = 1; off < 64; off <<= 1) {
            s1 += __shfl_xor(s1, off, 64);
            s2 += __shfl_xor(s2, off, 64);
        }
        float mu = s1 * (1.f / 64.f);
        float var = s2 * (1.f / 64.f) - mu * mu;
        float rstd = rsqrtf(var + 1e-6f);
        T[d * 17 + w * 4 + j] = (a[j] - mu) * rstd * g + be;
    }
    __syncthreads();
    int ch = t >> 2, part = t & 3;
    int hw0 = m0 & 1023;
    float4 v = {T[ch * 17 + part * 4 + 0], T[ch * 17 + part * 4 + 1],
                T[ch * 17 + part * 4 + 2], T[ch * 17 + part * 4 + 3]};
    *(float4*)&out[((size_t)b * 64 + ch) * 1024 + hw0 + part * 4] = v;
}

// ---------------- launcher: 6 dispatches ----------------
extern "C" void kernel_launch(void* const* d_in, const int* in_sizes, int n_in,
                              void* d_out, int out_size, void* d_ws, size_t ws_size,
                              hipStream_t stream) {
    const float* x      = (const float*)d_in[0];
    const float* memory = (const float*)d_in[1];
    const float* wb_w   = (const float*)d_in[2];
    const float* wb_b   = (const float*)d_in[3];
    const float* a1_wq  = (const float*)d_in[4];
    const float* a1_bq  = (const float*)d_in[5];
    const float* a1_wk  = (const float*)d_in[6];
    const float* a1_bk  = (const float*)d_in[7];
    const float* a1_wv  = (const float*)d_in[8];
    const float* a1_bv  = (const float*)d_in[9];
    const float* a1_fc  = (const float*)d_in[10];
    const float* a1_fcb = (const float*)d_in[11];
    const float* a1_ln_g = (const float*)d_in[12];
    const float* a1_ln_b = (const float*)d_in[13];
    const float* a2_wq  = (const float*)d_in[14];
    const float* a2_bq  = (const float*)d_in[15];
    const float* a2_wk  = (const float*)d_in[16];
    const float* a2_bk  = (const float*)d_in[17];
    const float* a2_wv  = (const float*)d_in[18];
    const float* a2_bv  = (const float*)d_in[19];
    const float* a2_fc  = (const float*)d_in[20];
    const float* a2_fcb = (const float*)d_in[21];
    const float* a2_ln_g = (const float*)d_in[22];
    const float* a2_ln_b = (const float*)d_in[23];

    float* ws = (float*)d_ws;
    float* logitsT = ws;                                   // 81920 f
    float* w1  = logitsT + 81920;                          // 81920 f
    float* cf1 = w1 + 81920;                               // 5120 f
    float* cfs = cf1 + 5120;                               // 5120 f
    float* sP0 = cfs + 5120;                               // 65536 f
    float* sP1 = sP0 + 65536;                              // 65536 f
    ushort_t* aoP0 = (ushort_t*)(sP1 + 65536);             // 4,194,304 ushorts each
    ushort_t* aoP1 = aoP0 + 4194304;
    ushort_t* Qb = aoP1 + 4194304;
    ushort_t* Kb = Qb + 4194304;
    ushort_t* Vt = Kb + 4194304;                           // total ~43 MB

    k1_logits<<<256, 64, 0, stream>>>(x, wb_w, wb_b, logitsT, w1);
    k2b_pool<<<256, 256, 0, stream>>>(x, logitsT, cf1);
    k3_mha1<<<16, 256, 0, stream>>>(cf1, a1_wq, a1_bq, memory, a1_wk, a1_bk,
                                    a1_wv, a1_bv, a1_fc, a1_fcb,
                                    a1_ln_g, a1_ln_b, cfs);
    k5_mfma<<<dim3(256, 3), 256, 0, stream>>>(w1, cfs, a2_wq, a2_bq, a2_wk, a2_bk,
                                              a2_wv, a2_bv, Qb, Kb, Vt);
    k6_attn<<<512, 256, 0, stream>>>(Qb, Kb, Vt, aoP0, aoP1, sP0, sP1);
    k7_final<<<1024, 256, 0, stream>>>(aoP0, aoP1, sP0, sP1, w1, cfs, a2_fc, a2_fcb,
                                       a2_ln_g, a2_ln_b, (float*)d_out);
}

// Round 13
// 191.453 us; speedup vs baseline: 1.5974x; 1.0579x over previous
//
#include <hip/hip_runtime.h>
#include <math.h>

typedef unsigned short ushort_t;
typedef __attribute__((ext_vector_type(8))) short short8;
typedef __attribute__((ext_vector_type(4))) float f32x4;

#define B_  16
#define HW_ 1024
#define C_  64
#define NC_ 5
#define D1_ 96
#define NH_ 4
#define DH_ 64

#define MFMA32(A,B,C) __builtin_amdgcn_mfma_f32_16x16x32_bf16(A,B,C,0,0,0)

__device__ __forceinline__ ushort_t f2bf(float f) {
    unsigned u = __float_as_uint(f);
    u = u + 0x7fffu + ((u >> 16) & 1u);   // round-to-nearest-even
    return (ushort_t)(u >> 16);
}

// truncating bf16 pair-pack: one op per 2 elements (lo -> low short, hi -> high short)
__device__ __forceinline__ unsigned pack2_trunc(float lo, float hi) {
    return (__float_as_uint(hi) & 0xffff0000u) | (__float_as_uint(lo) >> 16);
}
__device__ __forceinline__ unsigned pack2_rne(float lo, float hi) {
    return ((unsigned)f2bf(hi) << 16) | (unsigned)f2bf(lo);
}
__device__ __forceinline__ float bf_lo(unsigned u) { return __uint_as_float(u << 16); }
__device__ __forceinline__ float bf_hi(unsigned u) { return __uint_as_float(u & 0xffff0000u); }

// async global->LDS, 16B per lane; LDS dest = wave-uniform base + lane*16
__device__ __forceinline__ void gload16(const ushort_t* g, ushort_t* l) {
    __builtin_amdgcn_global_load_lds(
        (const __attribute__((address_space(1))) unsigned int*)g,
        (__attribute__((address_space(3))) unsigned int*)l,
        16, 0, 0);
}

// ---------------- K0: pre-pack fc^T into bf16 fragment-order buffer ----------------
// chunk c = (n*8+s)*64 + l : element j = fc[(s*32+(l>>4)*8+j)*64 + n*16+(l&15)]
__global__ __launch_bounds__(256) void k0_fcT(const float* __restrict__ fc,
                                              ushort_t* __restrict__ F) {
    int c = blockIdx.x * 256 + threadIdx.x;       // 0..2047
    int l = c & 63, s = (c >> 6) & 7, n = c >> 9;
    int col = n * 16 + (l & 15);
    int k0 = s * 32 + (l >> 4) * 8;
    union { ushort_t us[8]; uint4 u; } pk;
#pragma unroll
    for (int j = 0; j < 8; j++) pk.us[j] = f2bf(fc[(k0 + j) * 64 + col]);
    *(uint4*)(F + (size_t)c * 8) = pk.u;
}

// ---------------- K1: logits = xt @ wb_w + wb_b ; weight1 = softmax over classes ----------------
__global__ __launch_bounds__(64) void k1_logits(const float* __restrict__ x,
                                                const float* __restrict__ wb_w,
                                                const float* __restrict__ wb_b,
                                                float* __restrict__ logitsT,
                                                float* __restrict__ w1) {
    int b = blockIdx.x >> 4;
    int hw = (blockIdx.x & 15) * 64 + threadIdx.x;
    const float* xb = x + (size_t)b * C_ * HW_;
    float acc[NC_];
#pragma unroll
    for (int j = 0; j < NC_; j++) acc[j] = wb_b[j];
#pragma unroll 8
    for (int c = 0; c < C_; c++) {
        float xv = xb[c * HW_ + hw];
#pragma unroll
        for (int j = 0; j < NC_; j++) acc[j] += xv * wb_w[c * NC_ + j];
    }
    float m = acc[0];
#pragma unroll
    for (int j = 1; j < NC_; j++) m = fmaxf(m, acc[j]);
    float e[NC_], s = 0.f;
#pragma unroll
    for (int j = 0; j < NC_; j++) { e[j] = __expf(acc[j] - m); s += e[j]; }
    float inv = 1.f / s;
    int idx = b * HW_ + hw;
#pragma unroll
    for (int j = 0; j < NC_; j++) {
        logitsT[((size_t)b * NC_ + j) * HW_ + hw] = acc[j];
        w1[(size_t)idx * NC_ + j] = e[j] * inv;
    }
}

// ---------------- K2: fused softmax-over-HW + pooling: cf1[b,c,ch] ----------------
__global__ __launch_bounds__(256) void k2b_pool(const float* __restrict__ x,
                                                const float* __restrict__ logitsT,
                                                float* __restrict__ cf1) {
    __shared__ float pl[NC_ * HW_];     // 20 KB
    __shared__ float sinv[NC_];
    int t = threadIdx.x;
    int b = blockIdx.x >> 4, chg = blockIdx.x & 15;
    const float* lp = logitsT + (size_t)b * NC_ * HW_;
    for (int i = t * 4; i < NC_ * HW_; i += 1024)
        *(float4*)(pl + i) = *(const float4*)(lp + i);
    __syncthreads();
    int w = t >> 6, lane = t & 63;
    for (int r = w; r < NC_; r += 4) {
        float m = -1e30f;
        for (int i = lane; i < HW_; i += 64) m = fmaxf(m, pl[r * HW_ + i]);
#pragma unroll
        for (int off = 1; off < 64; off <<= 1) m = fmaxf(m, __shfl_xor(m, off, 64));
        float s = 0.f;
        for (int i = lane; i < HW_; i += 64) {
            float e = __expf(pl[r * HW_ + i] - m);
            pl[r * HW_ + i] = e;
            s += e;
        }
#pragma unroll
        for (int off = 1; off < 64; off <<= 1) s += __shfl_xor(s, off, 64);
        if (lane == 0) sinv[r] = 1.f / s;
    }
    __syncthreads();
    int ch = chg * 4 + w;
    const float* xc = x + ((size_t)b * C_ + ch) * HW_;
    float acc[NC_] = {0.f, 0.f, 0.f, 0.f, 0.f};
#pragma unroll
    for (int i = 0; i < HW_ / 64; i++) {
        int hw = i * 64 + lane;
        float xv = xc[hw];
#pragma unroll
        for (int c = 0; c < NC_; c++) acc[c] += xv * pl[c * HW_ + hw];
    }
#pragma unroll
    for (int c = 0; c < NC_; c++) {
        float a = acc[c];
#pragma unroll
        for (int off = 1; off < 64; off <<= 1) a += __shfl_xor(a, off, 64);
        if (lane == 0) cf1[((size_t)b * NC_ + c) * C_ + ch] = a * sinv[c];
    }
}

// ---------------- K3: MHA1 (n_head=1, dk=96, dv=64) + residual + LN, per batch ----------------
__global__ __launch_bounds__(256) void k3_mha1(const float* __restrict__ cf1,
                                               const float* __restrict__ wq, const float* __restrict__ bq,
                                               const float* __restrict__ mem,
                                               const float* __restrict__ wk, const float* __restrict__ bk,
                                               const float* __restrict__ wv, const float* __restrict__ bv,
                                               const float* __restrict__ fc, const float* __restrict__ fcb,
                                               const float* __restrict__ lng, const float* __restrict__ lnb,
                                               float* __restrict__ cfs) {
    __shared__ float cs[NC_ * C_];
    __shared__ float kh[NC_ * D1_];
    __shared__ float vh[NC_ * DH_];
    __shared__ float q[NC_ * D1_];
    __shared__ float sc[NC_ * NC_];
    __shared__ float pp[NC_ * NC_];
    __shared__ float o[NC_ * C_];
    __shared__ float z[NC_ * C_];
    __shared__ float mu[NC_], rs[NC_];
    int t = threadIdx.x, b = blockIdx.x;
    for (int i = t; i < NC_ * C_; i += 256) cs[i] = cf1[(size_t)b * NC_ * C_ + i];
    for (int idx = t; idx < NC_ * D1_; idx += 256) {
        int i = idx / D1_, k = idx % D1_;
        float a = bk[k];
        for (int d = 0; d < D1_; d++) a += mem[i * D1_ + d] * wk[d * D1_ + k];
        kh[idx] = a;
    }
    for (int idx = t; idx < NC_ * DH_; idx += 256) {
        int i = idx / DH_, dv = idx % DH_;
        float a = bv[dv];
        for (int d = 0; d < D1_; d++) a += mem[i * D1_ + d] * wv[d * DH_ + dv];
        vh[idx] = a;
    }
    __syncthreads();
    for (int idx = t; idx < NC_ * D1_; idx += 256) {
        int i = idx / D1_, k = idx % D1_;
        float a = bq[k];
        for (int c = 0; c < C_; c++) a += cs[i * C_ + c] * wq[c * D1_ + k];
        q[idx] = a;
    }
    __syncthreads();
    if (t < NC_ * NC_) {
        int i = t / NC_, j = t % NC_;
        float a = 0.f;
        for (int k = 0; k < D1_; k++) a += q[i * D1_ + k] * kh[j * D1_ + k];
        sc[t] = a * 0.1020620726159657f;     // 1/sqrt(96)
    }
    __syncthreads();
    if (t < NC_) {
        float m = sc[t * NC_];
        for (int j = 1; j < NC_; j++) m = fmaxf(m, sc[t * NC_ + j]);
        float e[NC_], s = 0.f;
        for (int j = 0; j < NC_; j++) { e[j] = __expf(sc[t * NC_ + j] - m); s += e[j]; }
        float inv = 1.f / s;
        for (int j = 0; j < NC_; j++) pp[t * NC_ + j] = e[j] * inv;
    }
    __syncthreads();
    for (int idx = t; idx < NC_ * C_; idx += 256) {
        int i = idx / C_, dv = idx % C_;
        float a = 0.f;
        for (int j = 0; j < NC_; j++) a += pp[i * NC_ + j] * vh[j * C_ + dv];
        o[idx] = a;
    }
    __syncthreads();
    for (int idx = t; idx < NC_ * C_; idx += 256) {
        int i = idx / C_, dd = idx % C_;
        float a = fcb[dd] + cs[idx];
        for (int c2 = 0; c2 < C_; c2++) a += o[i * C_ + c2] * fc[c2 * C_ + dd];
        z[idx] = a;
    }
    __syncthreads();
    if (t < NC_) {
        float s = 0.f;
        for (int d = 0; d < C_; d++) s += z[t * C_ + d];
        float mm = s / C_;
        float v = 0.f;
        for (int d = 0; d < C_; d++) { float dd2 = z[t * C_ + d] - mm; v += dd2 * dd2; }
        mu[t] = mm; rs[t] = rsqrtf(v / C_ + 1e-6f);
    }
    __syncthreads();
    for (int idx = t; idx < NC_ * C_; idx += 256) {
        int i = idx / C_, dd = idx % C_;
        cfs[(size_t)b * NC_ * C_ + idx] = (z[idx] - mu[i]) * rs[i] * lng[dd] + lnb[dd];
    }
}

// ---------------- K5: MFMA projection GEMM (inline redistribution + Q/K/V) ----------------
__global__ __launch_bounds__(256) void k5_mfma(const float* __restrict__ w1,
                                               const float* __restrict__ cfs,
                                               const float* __restrict__ wq, const float* __restrict__ bq,
                                               const float* __restrict__ wk, const float* __restrict__ bk,
                                               const float* __restrict__ wv, const float* __restrict__ bv,
                                               ushort_t* __restrict__ Qb, ushort_t* __restrict__ Kb,
                                               ushort_t* __restrict__ Vt) {
    __shared__ ushort_t Af[64][68];      // cf rows, bf16
    __shared__ ushort_t Wt[256][68];     // W^T [n][k], bf16
    int t = threadIdx.x;
    int which = blockIdx.y;
    int m0 = blockIdx.x * 64;
    int b = m0 >> 10, lbase = m0 & 1023;
    {
        int r = t >> 2, ks = (t & 3) * 16;
        const float* cp = cfs + (size_t)b * NC_ * C_;
        const float* w1p = w1 + (size_t)(m0 + r) * NC_;
        float v0 = w1p[0], v1 = w1p[1], v2 = w1p[2], v3 = w1p[3], v4 = w1p[4];
#pragma unroll
        for (int j = 0; j < 16; j += 2) {
            int k = ks + j;
            float e0 = v0 * cp[k]       + v1 * cp[64 + k]     + v2 * cp[128 + k]
                     + v3 * cp[192 + k] + v4 * cp[256 + k];
            float e1 = v0 * cp[k + 1]     + v1 * cp[64 + k + 1] + v2 * cp[128 + k + 1]
                     + v3 * cp[192 + k + 1] + v4 * cp[256 + k + 1];
            *(unsigned*)&Af[r][k] = pack2_rne(e0, e1);
        }
    }
    const float* W = (which == 0) ? wq : (which == 1) ? wk : wv;
    {
        int n = t;
#pragma unroll
        for (int k = 0; k < 64; k += 2) {
            *(unsigned*)&Wt[n][k] = pack2_rne(W[k * 256 + n], W[(k + 1) * 256 + n]);
        }
    }
    __syncthreads();
    int lane = t & 63, w = t >> 6;
    int l15 = lane & 15, quad = lane >> 4;
    if (which < 2) {
        const float* bias = (which == 0) ? bq : bk;
        float scale = (which == 0) ? 0.18033688011112042f : 1.0f;  // log2e/8 folded into Q
        ushort_t* dst = (which == 0) ? Qb : Kb;
        short8 a0[4], a1[4];
#pragma unroll
        for (int mi = 0; mi < 4; mi++) {
            a0[mi] = *(const short8*)&Af[mi * 16 + l15][quad * 8];
            a1[mi] = *(const short8*)&Af[mi * 16 + l15][32 + quad * 8];
        }
#pragma unroll
        for (int nt = 0; nt < 4; nt++) {
            int ni = w * 4 + nt;
            short8 b0 = *(const short8*)&Wt[ni * 16 + l15][quad * 8];
            short8 b1 = *(const short8*)&Wt[ni * 16 + l15][32 + quad * 8];
            int n = ni * 16 + l15;
            float bb = bias[n];
            int h = n >> 6, dd = n & 63;
#pragma unroll
            for (int mi = 0; mi < 4; mi++) {
                f32x4 z = {0, 0, 0, 0};
                f32x4 dv4 = MFMA32(a0[mi], b0, z);
                dv4 = MFMA32(a1[mi], b1, dv4);
                size_t base = ((size_t)(b * NH_ + h) * HW_ + (lbase + mi * 16 + quad * 4)) * DH_ + dd;
#pragma unroll
                for (int r = 0; r < 4; r++)
                    dst[base + (size_t)r * DH_] = f2bf((dv4[r] + bb) * scale);
            }
        }
    } else {
        short8 a0[4], a1[4];
#pragma unroll
        for (int mt = 0; mt < 4; mt++) {
            int mi = w * 4 + mt;
            a0[mt] = *(const short8*)&Wt[mi * 16 + l15][quad * 8];
            a1[mt] = *(const short8*)&Wt[mi * 16 + l15][32 + quad * 8];
        }
#pragma unroll
        for (int nt = 0; nt < 4; nt++) {
            short8 b0 = *(const short8*)&Af[nt * 16 + l15][quad * 8];
            short8 b1 = *(const short8*)&Af[nt * 16 + l15][32 + quad * 8];
#pragma unroll
            for (int mt = 0; mt < 4; mt++) {
                int mi = w * 4 + mt;
                f32x4 z = {0, 0, 0, 0};
                f32x4 dv4 = MFMA32(a0[mt], b0, z);
                dv4 = MFMA32(a1[mt], b1, dv4);
                int h = mi >> 2;
#pragma unroll
                for (int r = 0; r < 4; r++) {
                    int nw = mi * 16 + quad * 4 + r;
                    int dv = nw & 63;
                    Vt[((size_t)(b * NH_ + h) * DH_ + dv) * HW_ + lbase + nt * 16 + l15] =
                        f2bf(dv4[r] + bv[nw]);
                }
            }
        }
    }
}

// ---------------- K6: flash attention — async LDS staging (fragment-order), split-K2, 4 q-tiles ----
// Staging wave-lane loads exactly the global 16B the compute-lane needs -> LDS layout is
// chunk + lane*16 (conflict-free ds_read_b128). 8 chunks x 1KB per iter, double-buffered,
// ONE barrier/iter: stage(kt+1) flies during compute(kt) with zero VGPR cost.
__global__ __launch_bounds__(256) void k6_attn(const ushort_t* __restrict__ Qb,
                                               const ushort_t* __restrict__ Kb,
                                               const ushort_t* __restrict__ Vt,
                                               ushort_t* __restrict__ aoP0, ushort_t* __restrict__ aoP1,
                                               float* __restrict__ sP0, float* __restrict__ sP1) {
    __shared__ ushort_t Kst[2][8][512];     // 16 KB
    int t = threadIdx.x;
    int w = t >> 6;
    int lane = t & 63;
    int l15 = lane & 15;
    int quad = lane >> 4;
    // decode swizzled block id (grid 512): [2:0]=bh_lo, [5:3]=bh_hi, [6]=khalf, [8:7]=qt
    int L = blockIdx.x;
    int bh = ((L >> 3) & 7) * 8 + (L & 7);
    int khalf = (L >> 6) & 1;
    int qt = L >> 7;                     // 0..3
    int b = bh >> 2, h = bh & 3;
    const ushort_t* Qp = Qb + (size_t)bh * HW_ * DH_;
    const ushort_t* Kp = Kb + (size_t)bh * HW_ * DH_;
    const ushort_t* Vp = Vt + (size_t)bh * DH_ * HW_;
    int row0 = qt * 256 + w * 16;
    short8 q0[4], q1[4];
#pragma unroll
    for (int tl = 0; tl < 4; tl++) {
        const ushort_t* qp = Qp + (size_t)(row0 + tl * 64 + l15) * DH_ + quad * 8;
        q0[tl] = *(const short8*)(qp);
        q1[tl] = *(const short8*)(qp + 32);
    }
    // permuted key offsets: S^T tile0 row l15 -> key f0, tile1 -> f0+4
    int f0 = ((l15 >> 2) * 8) + (l15 & 3);
    int kstart = khalf * 512;
    const ushort_t* K0p = Kp + (size_t)(kstart + f0) * DH_ + quad * 8;
    const ushort_t* K1p = Kp + (size_t)(kstart + f0 + 4) * DH_ + quad * 8;
    const ushort_t* Vp0 = Vp + (size_t)(0 * 16 + l15) * HW_ + kstart + quad * 8;
    const ushort_t* Vp1 = Vp + (size_t)(1 * 16 + l15) * HW_ + kstart + quad * 8;
    const ushort_t* Vp2 = Vp + (size_t)(2 * 16 + l15) * HW_ + kstart + quad * 8;
    const ushort_t* Vp3 = Vp + (size_t)(3 * 16 + l15) * HW_ + kstart + quad * 8;
    auto stage = [&](int kt, int bb) {
        size_t koff = (size_t)kt * 32 * DH_;
        int kb32 = kt * 32;
        if (w == 0) {
            gload16(K0p + koff,      &Kst[bb][0][0]);
            gload16(K0p + koff + 32, &Kst[bb][1][0]);
        } else if (w == 1) {
            gload16(K1p + koff,      &Kst[bb][2][0]);
            gload16(K1p + koff + 32, &Kst[bb][3][0]);
        } else if (w == 2) {
            gload16(Vp0 + kb32, &Kst[bb][4][0]);
            gload16(Vp1 + kb32, &Kst[bb][5][0]);
        } else {
            gload16(Vp2 + kb32, &Kst[bb][6][0]);
            gload16(Vp3 + kb32, &Kst[bb][7][0]);
        }
    };
    const short ONE = (short)0x3F80;      // bf16 1.0
    short8 ones = {ONE, ONE, ONE, ONE, ONE, ONE, ONE, ONE};
    f32x4 o0[4], o1[4], o2[4], o3[4], oS[4];
#pragma unroll
    for (int tl = 0; tl < 4; tl++) {
        o0[tl] = (f32x4){0,0,0,0}; o1[tl] = (f32x4){0,0,0,0};
        o2[tl] = (f32x4){0,0,0,0}; o3[tl] = (f32x4){0,0,0,0};
        oS[tl] = (f32x4){0,0,0,0};
    }
    stage(0, 0);
    for (int kt = 0; kt < 16; kt++) {
        int bb = kt & 1;
        __syncthreads();                     // stage(kt) complete (compiler drains vmcnt)
        if (kt < 15) stage(kt + 1, bb ^ 1);  // flies during compute below
        const ushort_t* S = &Kst[bb][0][0];
        short8 ka0 = *(const short8*)(S + 0 * 512 + lane * 8);
        short8 ka1 = *(const short8*)(S + 1 * 512 + lane * 8);
        short8 kb0 = *(const short8*)(S + 2 * 512 + lane * 8);
        short8 kb1 = *(const short8*)(S + 3 * 512 + lane * 8);
        short8 v0  = *(const short8*)(S + 4 * 512 + lane * 8);
        short8 v1  = *(const short8*)(S + 5 * 512 + lane * 8);
        short8 v2  = *(const short8*)(S + 6 * 512 + lane * 8);
        short8 v3  = *(const short8*)(S + 7 * 512 + lane * 8);
        f32x4 z = {0,0,0,0};
#pragma unroll
        for (int tl = 0; tl < 4; tl++) {
            f32x4 s0 = MFMA32(ka0, q0[tl], z);  s0 = MFMA32(ka1, q1[tl], s0);
            f32x4 s1 = MFMA32(kb0, q0[tl], z);  s1 = MFMA32(kb1, q1[tl], s1);
            float p0 = exp2f(s0[0]), p1 = exp2f(s0[1]), p2 = exp2f(s0[2]), p3 = exp2f(s0[3]);
            float p4 = exp2f(s1[0]), p5 = exp2f(s1[1]), p6 = exp2f(s1[2]), p7 = exp2f(s1[3]);
            union { short8 v; unsigned u[4]; } pf;
            pf.u[0] = pack2_trunc(p0, p1);  pf.u[1] = pack2_trunc(p2, p3);
            pf.u[2] = pack2_trunc(p4, p5);  pf.u[3] = pack2_trunc(p6, p7);
            o0[tl] = MFMA32(v0, pf.v, o0[tl]);
            o1[tl] = MFMA32(v1, pf.v, o1[tl]);
            o2[tl] = MFMA32(v2, pf.v, o2[tl]);
            o3[tl] = MFMA32(v3, pf.v, o3[tl]);
            oS[tl] = MFMA32(ones, pf.v, oS[tl]);
        }
    }
    ushort_t* aoP = khalf ? aoP1 : aoP0;
    float* sP = khalf ? sP1 : sP0;
#pragma unroll
    for (int tl = 0; tl < 4; tl++) {
        int rowg = row0 + tl * 64 + l15;
        ushort_t* aop = aoP + ((size_t)(b * HW_ + rowg)) * 256 + h * 64 + quad * 4;
        uint2 u;
        u.x = pack2_trunc(o0[tl][0], o0[tl][1]); u.y = pack2_trunc(o0[tl][2], o0[tl][3]);
        *(uint2*)(aop + 0) = u;
        u.x = pack2_trunc(o1[tl][0], o1[tl][1]); u.y = pack2_trunc(o1[tl][2], o1[tl][3]);
        *(uint2*)(aop + 16) = u;
        u.x = pack2_trunc(o2[tl][0], o2[tl][1]); u.y = pack2_trunc(o2[tl][2], o2[tl][3]);
        *(uint2*)(aop + 32) = u;
        u.x = pack2_trunc(o3[tl][0], o3[tl][1]); u.y = pack2_trunc(o3[tl][2], o3[tl][3]);
        *(uint2*)(aop + 48) = u;
        if (quad == 0)
            sP[(size_t)(b * HW_ + rowg) * NH_ + h] = oS[tl][0];
    }
}

// ---------------- K7: combine partials -> MFMA GEMM vs fc + residual + LN -> out ----------------
// A (16x256) built in fragment-order LDS from aoP partials; B frags loaded coalesced from k0's
// frag-order fcT buffer; 8 MFMAs per wave (one 16-col N-tile) replace 256 ds_read + 1024 FMA.
__global__ __launch_bounds__(256) void k7_final(const ushort_t* __restrict__ aoP0,
                                                const ushort_t* __restrict__ aoP1,
                                                const float* __restrict__ sP0,
                                                const float* __restrict__ sP1,
                                                const float* __restrict__ w1,
                                                const float* __restrict__ cfs,
                                                const ushort_t* __restrict__ F,
                                                const float* __restrict__ fcb,
                                                const float* __restrict__ lng, const float* __restrict__ lnb,
                                                float* __restrict__ out) {
    __shared__ ushort_t Afr[512 * 8];     // 8 KB fragment-order A
    __shared__ float rinv[64];
    __shared__ float T[16][68];           // MFMA result f32 (padded)
    __shared__ float To[64 * 17];         // output transpose buffer
    int t = threadIdx.x, w = t >> 6, lane = t & 63;
    int m0 = blockIdx.x * 16, b = m0 >> 10;   // m0 is the GLOBAL row index (includes b*1024)
    if (t < 64) {
        int row = t >> 2, hh = t & 3;
        float s = sP0[(size_t)(m0 + row) * NH_ + hh] + sP1[(size_t)(m0 + row) * NH_ + hh];
        rinv[t] = 1.f / s;
    }
    __syncthreads();
    // build A fragments: chunk cc=(s*64+l): A[l&15][s*32+(l>>4)*8 + j]
#pragma unroll
    for (int cc = t; cc < 512; cc += 256) {
        int s = cc >> 6, l = cc & 63;
        int row = l & 15, col0 = s * 32 + (l >> 4) * 8;
        int hh = col0 >> 6;
        size_t base = (size_t)(m0 + row) * 256 + col0;   // FIXED: m0 already global (R12 bug: +b*HW_)
        uint4 a = *(const uint4*)(aoP0 + base);
        uint4 c4 = *(const uint4*)(aoP1 + base);
        float r = rinv[row * 4 + hh];
        uint4 pk;
        pk.x = pack2_trunc((bf_lo(a.x) + bf_lo(c4.x)) * r, (bf_hi(a.x) + bf_hi(c4.x)) * r);
        pk.y = pack2_trunc((bf_lo(a.y) + bf_lo(c4.y)) * r, (bf_hi(a.y) + bf_hi(c4.y)) * r);
        pk.z = pack2_trunc((bf_lo(a.z) + bf_lo(c4.z)) * r, (bf_hi(a.z) + bf_hi(c4.z)) * r);
        pk.w = pack2_trunc((bf_lo(a.w) + bf_lo(c4.w)) * r, (bf_hi(a.w) + bf_hi(c4.w)) * r);
        *(uint4*)&Afr[(size_t)cc * 8] = pk;
    }
    __syncthreads();
    // GEMM: wave w -> N-tile w (cols w*16..w*16+15)
    f32x4 acc = {0, 0, 0, 0};
#pragma unroll
    for (int s = 0; s < 8; s++) {
        short8 a = *(const short8*)&Afr[(s * 64 + lane) * 8];
        short8 bf8 = *(const short8*)(F + ((size_t)(w * 8 + s) * 64 + lane) * 8);
        acc = MFMA32(a, bf8, acc);
    }
    {
        int l15 = lane & 15, quad = lane >> 4;
#pragma unroll
        for (int r = 0; r < 4; r++) T[quad * 4 + r][w * 16 + l15] = acc[r];
    }
    __syncthreads();
    // LN (+ bias + inline redistribution residual), rows w*4+j, lane = d
    int d = lane;
    float g = lng[d], be = lnb[d], bias = fcb[d];
    const float* cp = cfs + (size_t)b * NC_ * C_;
#pragma unroll
    for (int j = 0; j < 4; j++) {
        int row = w * 4 + j;
        const float* w1p = w1 + (size_t)(m0 + row) * NC_;
        float a = bias + T[row][d];
#pragma unroll
        for (int c = 0; c < NC_; c++) a += w1p[c] * cp[c * 64 + d];
        float s1 = a, s2 = a * a;
#pragma unroll
        for (int off = 1; off < 64; off <<= 1) {
            s1 += __shfl_xor(s1, off, 64);
            s2 += __shfl_xor(s2, off, 64);
        }
        float mu = s1 * (1.f / 64.f);
        float var = s2 * (1.f / 64.f) - mu * mu;
        float rstd = rsqrtf(var + 1e-6f);
        To[d * 17 + row] = (a - mu) * rstd * g + be;
    }
    __syncthreads();
    int ch = t >> 2, part = t & 3;
    int hw0 = m0 & 1023;
    float4 v = {To[ch * 17 + part * 4 + 0], To[ch * 17 + part * 4 + 1],
                To[ch * 17 + part * 4 + 2], To[ch * 17 + part * 4 + 3]};
    *(float4*)&out[((size_t)b * 64 + ch) * 1024 + hw0 + part * 4] = v;
}

// ---------------- launcher: 7 dispatches ----------------
extern "C" void kernel_launch(void* const* d_in, const int* in_sizes, int n_in,
                              void* d_out, int out_size, void* d_ws, size_t ws_size,
                              hipStream_t stream) {
    const float* x      = (const float*)d_in[0];
    const float* memory = (const float*)d_in[1];
    const float* wb_w   = (const float*)d_in[2];
    const float* wb_b   = (const float*)d_in[3];
    const float* a1_wq  = (const float*)d_in[4];
    const float* a1_bq  = (const float*)d_in[5];
    const float* a1_wk  = (const float*)d_in[6];
    const float* a1_bk  = (const float*)d_in[7];
    const float* a1_wv  = (const float*)d_in[8];
    const float* a1_bv  = (const float*)d_in[9];
    const float* a1_fc  = (const float*)d_in[10];
    const float* a1_fcb = (const float*)d_in[11];
    const float* a1_ln_g = (const float*)d_in[12];
    const float* a1_ln_b = (const float*)d_in[13];
    const float* a2_wq  = (const float*)d_in[14];
    const float* a2_bq  = (const float*)d_in[15];
    const float* a2_wk  = (const float*)d_in[16];
    const float* a2_bk  = (const float*)d_in[17];
    const float* a2_wv  = (const float*)d_in[18];
    const float* a2_bv  = (const float*)d_in[19];
    const float* a2_fc  = (const float*)d_in[20];
    const float* a2_fcb = (const float*)d_in[21];
    const float* a2_ln_g = (const float*)d_in[22];
    const float* a2_ln_b = (const float*)d_in[23];

    float* ws = (float*)d_ws;
    float* logitsT = ws;                                   // 81920 f
    float* w1  = logitsT + 81920;                          // 81920 f
    float* cf1 = w1 + 81920;                               // 5120 f
    float* cfs = cf1 + 5120;                               // 5120 f
    float* sP0 = cfs + 5120;                               // 65536 f
    float* sP1 = sP0 + 65536;                              // 65536 f
    ushort_t* aoP0 = (ushort_t*)(sP1 + 65536);             // 4,194,304 ushorts each
    ushort_t* aoP1 = aoP0 + 4194304;
    ushort_t* Qb = aoP1 + 4194304;
    ushort_t* Kb = Qb + 4194304;
    ushort_t* Vt = Kb + 4194304;
    ushort_t* F  = Vt + 4194304;                           // 16384 ushorts (fcT frag-order)

    k0_fcT<<<8, 256, 0, stream>>>(a2_fc, F);
    k1_logits<<<256, 64, 0, stream>>>(x, wb_w, wb_b, logitsT, w1);
    k2b_pool<<<256, 256, 0, stream>>>(x, logitsT, cf1);
    k3_mha1<<<16, 256, 0, stream>>>(cf1, a1_wq, a1_bq, memory, a1_wk, a1_bk,
                                    a1_wv, a1_bv, a1_fc, a1_fcb,
                                    a1_ln_g, a1_ln_b, cfs);
    k5_mfma<<<dim3(256, 3), 256, 0, stream>>>(w1, cfs, a2_wq, a2_bq, a2_wk, a2_bk,
                                              a2_wv, a2_bv, Qb, Kb, Vt);
    k6_attn<<<512, 256, 0, stream>>>(Qb, Kb, Vt, aoP0, aoP1, sP0, sP1);
    k7_final<<<1024, 256, 0, stream>>>(aoP0, aoP1, sP0, sP1, w1, cfs, F, a2_fcb,
                                       a2_ln_g, a2_ln_b, (float*)d_out);
}